// Round 5
// baseline (244.957 us; speedup 1.0000x reference)
//
#include <hip/hip_runtime.h>

#define Bq 64
#define Sq 256
#define Dq 768
#define CAPq 8
#define NTq 10
#define SCq 2048   // S*CAP

// ---------------- Kernel 1: sem[b,s,c,n] = x[b,s,:]·fc1_w[n,c,:] + b, squash over n,
// write u[b][n][s*8+c]  (u is [B][NT][S*CAP])
__global__ __launch_bounds__(256) void k1_sem(const float* __restrict__ x,
                                              const float* __restrict__ fc1w,
                                              const float* __restrict__ fc1b,
                                              float* __restrict__ u) {
    __shared__ float xs[64][33];
    __shared__ float ws[80][33];
    const int t = threadIdx.x;
    const int R0 = blockIdx.x * 64;           // global row = b*256 + s
    const int rp = t >> 3;                    // 0..31 -> rows 2rp, 2rp+1
    const int cc = t & 7;                     // capsule
    float acc0[NTq], acc1[NTq];
#pragma unroll
    for (int n = 0; n < NTq; ++n) { acc0[n] = 0.f; acc1[n] = 0.f; }

    for (int kc = 0; kc < Dq; kc += 32) {
#pragma unroll
        for (int i = 0; i < 2; ++i) {
            int lin = t + i * 256;            // 0..511
            int r = lin >> 3, k4 = (lin & 7) * 4;
            float4 v = *reinterpret_cast<const float4*>(&x[(size_t)(R0 + r) * Dq + kc + k4]);
            xs[r][k4] = v.x; xs[r][k4+1] = v.y; xs[r][k4+2] = v.z; xs[r][k4+3] = v.w;
        }
#pragma unroll
        for (int i = 0; i < 3; ++i) {
            int lin = t + i * 256;
            if (lin < 640) {                  // 80*32/4
                int o = lin >> 3, k4 = (lin & 7) * 4;
                float4 v = *reinterpret_cast<const float4*>(&fc1w[(size_t)o * Dq + kc + k4]);
                ws[o][k4] = v.x; ws[o][k4+1] = v.y; ws[o][k4+2] = v.z; ws[o][k4+3] = v.w;
            }
        }
        __syncthreads();
#pragma unroll
        for (int k = 0; k < 32; ++k) {
            float x0 = xs[2*rp][k], x1 = xs[2*rp+1][k];
#pragma unroll
            for (int n = 0; n < NTq; ++n) {
                float wv = ws[n*8 + cc][k];
                acc0[n] = fmaf(x0, wv, acc0[n]);
                acc1[n] = fmaf(x1, wv, acc1[n]);
            }
        }
        __syncthreads();
    }
    float sq0 = 0.f, sq1 = 0.f;
#pragma unroll
    for (int n = 0; n < NTq; ++n) {
        float bias = fc1b[n*8 + cc];
        acc0[n] += bias; acc1[n] += bias;
        sq0 = fmaf(acc0[n], acc0[n], sq0);
        sq1 = fmaf(acc1[n], acc1[n], sq1);
    }
    float sc0 = (sq0 / (1.f + sq0)) / sqrtf(sq0);
    float sc1 = (sq1 / (1.f + sq1)) / sqrtf(sq1);
    int row0 = R0 + 2*rp, row1 = row0 + 1;
    int b0 = row0 >> 8, s0 = row0 & 255;
    int b1 = row1 >> 8, s1 = row1 & 255;
#pragma unroll
    for (int n = 0; n < NTq; ++n) {
        u[(size_t)b0*(NTq*SCq) + n*SCq + s0*8 + cc] = acc0[n]*sc0;
        u[(size_t)b1*(NTq*SCq) + n*SCq + s1*8 + cc] = acc1[n]*sc1;
    }
}

// ---------------- Kernel 2: priors partials. part[ks][c][b][r][l] = sum_{k in half ks} u[b,r,k]*rw[c,r,k,l]
__global__ __launch_bounds__(256) void k2_priors(const float* __restrict__ u,
                                                 const float* __restrict__ rw,
                                                 float* __restrict__ part) {
    __shared__ float uS[64][33];
    __shared__ float wS[32][132];
    const int t = threadIdx.x;
    const int lt = blockIdx.x & 1;            // l-half
    const int ks = blockIdx.x >> 1;           // k-half
    const int r = blockIdx.y;
    const int c = blockIdx.z;
    const int tb = t >> 4, tl = t & 15;
    float acc[4][8];
#pragma unroll
    for (int i = 0; i < 4; ++i)
#pragma unroll
        for (int j = 0; j < 8; ++j) acc[i][j] = 0.f;

    const float* ub = u + (size_t)r * SCq + ks * 1024;                     // + b*NT*SC + k
    const float* wb = rw + ((size_t)(c*NTq + r) * SCq + ks*1024) * Sq + lt * 128;  // + k*S + l

    for (int kc = 0; kc < 1024; kc += 32) {
#pragma unroll
        for (int i = 0; i < 2; ++i) {
            int lin = t + i * 256;            // 0..511
            int bb = lin >> 3, k4 = (lin & 7) * 4;
            float4 v = *reinterpret_cast<const float4*>(&ub[(size_t)bb*(NTq*SCq) + kc + k4]);
            uS[bb][k4] = v.x; uS[bb][k4+1] = v.y; uS[bb][k4+2] = v.z; uS[bb][k4+3] = v.w;
        }
#pragma unroll
        for (int i = 0; i < 4; ++i) {
            int lin = t + i * 256;            // 0..1023
            int kk = lin >> 5, l4 = (lin & 31) * 4;
            float4 v = *reinterpret_cast<const float4*>(&wb[(size_t)(kc + kk)*Sq + l4]);
            *reinterpret_cast<float4*>(&wS[kk][l4]) = v;
        }
        __syncthreads();
#pragma unroll
        for (int kk = 0; kk < 32; ++kk) {
            float uv[4];
#pragma unroll
            for (int i = 0; i < 4; ++i) uv[i] = uS[tb + 16*i][kk];
            float4 w0 = *reinterpret_cast<const float4*>(&wS[kk][tl*4]);
            float4 w1 = *reinterpret_cast<const float4*>(&wS[kk][tl*4 + 64]);
#pragma unroll
            for (int i = 0; i < 4; ++i) {
                acc[i][0] = fmaf(uv[i], w0.x, acc[i][0]);
                acc[i][1] = fmaf(uv[i], w0.y, acc[i][1]);
                acc[i][2] = fmaf(uv[i], w0.z, acc[i][2]);
                acc[i][3] = fmaf(uv[i], w0.w, acc[i][3]);
                acc[i][4] = fmaf(uv[i], w1.x, acc[i][4]);
                acc[i][5] = fmaf(uv[i], w1.y, acc[i][5]);
                acc[i][6] = fmaf(uv[i], w1.z, acc[i][6]);
                acc[i][7] = fmaf(uv[i], w1.w, acc[i][7]);
            }
        }
        __syncthreads();
    }
#pragma unroll
    for (int i = 0; i < 4; ++i) {
        int bb = tb + 16*i;
        size_t base = ((((size_t)ks*CAPq + c)*Bq + bb)*NTq + r)*Sq + lt*128 + tl*4;
        *reinterpret_cast<float4*>(&part[base])      = make_float4(acc[i][0], acc[i][1], acc[i][2], acc[i][3]);
        *reinterpret_cast<float4*>(&part[base + 64]) = make_float4(acc[i][4], acc[i][5], acc[i][6], acc[i][7]);
    }
}

// ---------------- block reduce (256 threads)
__device__ __forceinline__ float block_reduce_sum(float v, float* red) {
#pragma unroll
    for (int o = 32; o > 0; o >>= 1) v += __shfl_xor(v, o, 64);
    int wid = threadIdx.x >> 6;
    if ((threadIdx.x & 63) == 0) red[wid] = v;
    __syncthreads();
    float r = red[0] + red[1] + red[2] + red[3];
    __syncthreads();
    return r;
}

// ---------------- Kernel 3: dynamic routing per (c,b). vote_out[c][b][l]
__global__ __launch_bounds__(256) void k3_route(const float* __restrict__ part,
                                                const int* __restrict__ task_p,
                                                float* __restrict__ vote_out) {
    __shared__ float pr[NTq][Sq];
    __shared__ float red[4];
    const int t = threadIdx.x;
    const int b = blockIdx.x & 63;
    const int c = blockIdx.x >> 6;
    const int task = *task_p;
    const size_t half = (size_t)CAPq * Bq * NTq * Sq;   // 1,310,720
    size_t base = ((size_t)(c*Bq + b) * NTq) * Sq;
#pragma unroll
    for (int r = 0; r < NTq; ++r)
        pr[r][t] = part[base + r*Sq + t] + part[half + base + r*Sq + t];
    __syncthreads();

    float logits[NTq];
#pragma unroll
    for (int r = 0; r < NTq; ++r) logits[r] = 0.f;
    float vote = 0.f;

    for (int it = 0; it < 3; ++it) {
        float m = -1e30f;
#pragma unroll
        for (int r = 0; r < NTq; ++r) if (r <= task) m = fmaxf(m, logits[r]);
        float p[NTq]; float s = 0.f;
#pragma unroll
        for (int r = 0; r < NTq; ++r) {
            p[r] = (r <= task) ? expf(logits[r] - m) : 0.f;
            s += p[r];
        }
        float inv = 1.f / s;
        vote = 0.f;
#pragma unroll
        for (int r = 0; r < NTq; ++r) vote = fmaf(p[r]*inv, pr[r][t], vote);
        if (it == 2) break;
        float sq = block_reduce_sum(vote*vote, red);
        float scale = (sq / (1.f + sq)) / sqrtf(sq);
        float outv = vote * scale;
#pragma unroll
        for (int r = 0; r < NTq; ++r) {
            float a = block_reduce_sum(pr[r][t] * outv, red);
            if (r <= task) logits[r] += a;
        }
    }
    vote_out[(size_t)(c*Bq + b)*Sq + t] = vote;
}

// ---------------- Kernel 4: h gather (flat reinterpret) + Linear(CAP->768)
__global__ __launch_bounds__(256) void k4_out(const float* __restrict__ vote, // [CAP][B][S] flat
                                              const float* __restrict__ lw,   // [768][8]
                                              const float* __restrict__ lb,   // [768]
                                              float* __restrict__ out) {      // [B,S,768]
    __shared__ float hS[8][8];
    const int t = threadIdx.x;
    if (t < 64) {
        int rr = t >> 3, cc = t & 7;
        size_t row = (size_t)blockIdx.x * 8 + rr;   // b'*256 + s'
        size_t flat = row * 8 + cc;                 // b'*2048 + s'*8 + c'
        int c = (int)(flat >> 14);                  // /16384
        int rem = (int)(flat & 16383);
        int bb = rem >> 8;
        int l = rem & 255;
        hS[rr][cc] = vote[(size_t)c*16384 + bb*256 + l];
    }
    float lwr[3][8];
    float lbr[3];
#pragma unroll
    for (int dd = 0; dd < 3; ++dd) {
        int d = t + dd*256;
        float4 a = *reinterpret_cast<const float4*>(&lw[(size_t)d*8]);
        float4 b2 = *reinterpret_cast<const float4*>(&lw[(size_t)d*8 + 4]);
        lwr[dd][0]=a.x; lwr[dd][1]=a.y; lwr[dd][2]=a.z; lwr[dd][3]=a.w;
        lwr[dd][4]=b2.x; lwr[dd][5]=b2.y; lwr[dd][6]=b2.z; lwr[dd][7]=b2.w;
        lbr[dd] = lb[d];
    }
    __syncthreads();
#pragma unroll
    for (int rr = 0; rr < 8; ++rr) {
        size_t row = (size_t)blockIdx.x * 8 + rr;
#pragma unroll
        for (int dd = 0; dd < 3; ++dd) {
            float acc = lbr[dd];
#pragma unroll
            for (int c = 0; c < 8; ++c) acc = fmaf(hS[rr][c], lwr[dd][c], acc);
            out[row*Dq + t + dd*256] = acc;
        }
    }
}

extern "C" void kernel_launch(void* const* d_in, const int* in_sizes, int n_in,
                              void* d_out, int out_size, void* d_ws, size_t ws_size,
                              hipStream_t stream) {
    const float* x    = (const float*)d_in[0];
    const int*   task = (const int*)d_in[1];
    const float* fc1w = (const float*)d_in[2];
    const float* fc1b = (const float*)d_in[3];
    const float* rw   = (const float*)d_in[4];
    const float* lw   = (const float*)d_in[5];
    const float* lb   = (const float*)d_in[6];
    float* out = (float*)d_out;

    float* u    = (float*)d_ws;                 // [64][10][2048]  = 1,310,720 f
    float* part = u + 1310720;                  // [2][8][64][10][256] = 2,621,440 f
    float* vote = part + 2*1310720;             // [8][64][256]    = 131,072 f

    k1_sem<<<256, 256, 0, stream>>>(x, fc1w, fc1b, u);
    dim3 g2(4, NTq, CAPq);
    k2_priors<<<g2, 256, 0, stream>>>(u, rw, part);
    k3_route<<<512, 256, 0, stream>>>(part, task, vote);
    k4_out<<<2048, 256, 0, stream>>>(vote, lw, lb, out);
}

// Round 7
// 179.372 us; speedup vs baseline: 1.3656x; 1.3656x over previous
//
#include <hip/hip_runtime.h>
#include <hip/hip_bf16.h>

#define Bq 64
#define Sq 256
#define Dq 768
#define CAPq 8
#define NTq 10
#define SCq 2048   // S*CAP

typedef short bf16x8 __attribute__((ext_vector_type(8)));
typedef float f32x4  __attribute__((ext_vector_type(4)));

// split f32 into hi/lo bf16 (bit-truncation; f ~= hi + lo, residual ~2^-17 |f|)
static __device__ __forceinline__ short bfhi(float f) {
    return (short)(__float_as_uint(f) >> 16);
}
static __device__ __forceinline__ short bflo(float f) {
    float hi = __uint_as_float(__float_as_uint(f) & 0xFFFF0000u);
    return (short)(__float_as_uint(f - hi) >> 16);
}

// ---------------- Kernel 1 (split-bf16 MFMA): sem = x·fc1w^T + b, squash over routes,
// write u as hi/lo bf16 pair, layout [B][NT][S*CAP].
// Block: 64 rows (b*256+s), 4 waves x 16 rows. N=80 = 5 frags of 16. K=768.
__global__ __launch_bounds__(256) void k1_sem(const float* __restrict__ x,
                                              const float* __restrict__ fc1w,
                                              const float* __restrict__ fc1b,
                                              short* __restrict__ u_hi,
                                              short* __restrict__ u_lo) {
    const int t = threadIdx.x;
    const int L = t & 63, w = t >> 6;
    const int colL = L & 15, kg = L >> 4;
    const int R0 = blockIdx.x * 64;
    const int rowA = R0 + w * 16 + colL;          // A-fragment row

    float bias[5];
#pragma unroll
    for (int f = 0; f < 5; ++f) bias[f] = fc1b[f * 16 + colL];

    f32x4 acc[5];
#pragma unroll
    for (int f = 0; f < 5; ++f) acc[f] = (f32x4){0.f, 0.f, 0.f, 0.f};

#pragma unroll 2
    for (int kc = 0; kc < Dq; kc += 32) {
        const int kbase = kc + kg * 8;
        const float* px = x + (size_t)rowA * Dq + kbase;
        float xv[8];
        *reinterpret_cast<float4*>(&xv[0]) = *reinterpret_cast<const float4*>(px);
        *reinterpret_cast<float4*>(&xv[4]) = *reinterpret_cast<const float4*>(px + 4);
        bf16x8 ah, al;
#pragma unroll
        for (int i = 0; i < 8; ++i) { ah[i] = bfhi(xv[i]); al[i] = bflo(xv[i]); }
#pragma unroll
        for (int f = 0; f < 5; ++f) {
            const float* pw = fc1w + (size_t)(f * 16 + colL) * Dq + kbase;
            float wv[8];
            *reinterpret_cast<float4*>(&wv[0]) = *reinterpret_cast<const float4*>(pw);
            *reinterpret_cast<float4*>(&wv[4]) = *reinterpret_cast<const float4*>(pw + 4);
            bf16x8 bh, bl;
#pragma unroll
            for (int i = 0; i < 8; ++i) { bh[i] = bfhi(wv[i]); bl[i] = bflo(wv[i]); }
            acc[f] = __builtin_amdgcn_mfma_f32_16x16x32_bf16(al, bh, acc[f], 0, 0, 0);
            acc[f] = __builtin_amdgcn_mfma_f32_16x16x32_bf16(ah, bl, acc[f], 0, 0, 0);
            acc[f] = __builtin_amdgcn_mfma_f32_16x16x32_bf16(ah, bh, acc[f], 0, 0, 0);
        }
    }

    // epilogue: bias + squash over the 10 routes of each (row, capsule)
    const int cc = colL & 7;
    const int npar = (colL >> 3) & 1;
#pragma unroll
    for (int reg = 0; reg < 4; ++reg) {
        const int row = R0 + w * 16 + kg * 4 + reg;    // C/D: row=(L>>4)*4+reg
        const int b = row >> 8, s = row & 255;
        float v[5], sqp = 0.f;
#pragma unroll
        for (int f = 0; f < 5; ++f) {
            v[f] = acc[f][reg] + bias[f];
            sqp = fmaf(v[f], v[f], sqp);
        }
        float sq = sqp + __shfl_xor(sqp, 8, 64);       // pair even/odd routes (colL ^ 8)
        float scale = (sq / (1.f + sq)) / sqrtf(sq);
#pragma unroll
        for (int f = 0; f < 5; ++f) {
            int n = 2 * f + npar;
            size_t off = ((size_t)b * NTq + n) * SCq + s * 8 + cc;
            float val = v[f] * scale;
            u_hi[off] = bfhi(val);
            u_lo[off] = bflo(val);
        }
    }
}

// ---------------- Kernel 2 (split-bf16 MFMA, LDS-free):
// part[ks][c][b][r][l] = sum_{k in half ks} u[b,r,k]*rw[c,r,k,l]
// grid.x: lq = x&3 (64-l quarter), ks = x>>2 (1024-k half); y=r, z=c.
// Masked routes (r > task) skipped entirely: softmax prob is exactly 0 there.
__global__ __launch_bounds__(256) void k2_priors(const short* __restrict__ u_hi,
                                                 const short* __restrict__ u_lo,
                                                 const float* __restrict__ rw,
                                                 const int* __restrict__ task_p,
                                                 float* __restrict__ part) {
    const int r = blockIdx.y;
    if (r > *task_p) return;
    const int t = threadIdx.x;
    const int L = t & 63, w = t >> 6;
    const int colL = L & 15, kg = L >> 4;
    const int lq = blockIdx.x & 3, ks = blockIdx.x >> 2;
    const int c = blockIdx.z;
    const int l = lq * 64 + w * 16 + colL;
    const int k00 = ks * 1024;

    f32x4 acc[4];
#pragma unroll
    for (int m = 0; m < 4; ++m) acc[m] = (f32x4){0.f, 0.f, 0.f, 0.f};

    const float* pbase = rw + ((size_t)(c * NTq + r) * SCq + k00 + kg * 8) * Sq + l;
    const size_t uoff = ((size_t)colL * NTq + r) * SCq + k00 + kg * 8;

#pragma unroll 2
    for (int kc = 0; kc < 1024; kc += 32) {
        // B fragment: 8 strided f32 loads (4x64B segments/instr), split to hi/lo bf16
        const float* pb = pbase + (size_t)kc * Sq;
        float bv[8];
#pragma unroll
        for (int i = 0; i < 8; ++i) bv[i] = pb[(size_t)i * Sq];
        bf16x8 bh, bl;
#pragma unroll
        for (int i = 0; i < 8; ++i) { bh[i] = bfhi(bv[i]); bl[i] = bflo(bv[i]); }
        // A fragments: u already split, 16B contiguous per lane
        bf16x8 ah[4], al[4];
#pragma unroll
        for (int m = 0; m < 4; ++m) {
            ah[m] = *reinterpret_cast<const bf16x8*>(u_hi + uoff + (size_t)(16 * m) * (NTq * SCq) + kc);
            al[m] = *reinterpret_cast<const bf16x8*>(u_lo + uoff + (size_t)(16 * m) * (NTq * SCq) + kc);
        }
#pragma unroll
        for (int m = 0; m < 4; ++m) {
            acc[m] = __builtin_amdgcn_mfma_f32_16x16x32_bf16(al[m], bh, acc[m], 0, 0, 0);
            acc[m] = __builtin_amdgcn_mfma_f32_16x16x32_bf16(ah[m], bl, acc[m], 0, 0, 0);
            acc[m] = __builtin_amdgcn_mfma_f32_16x16x32_bf16(ah[m], bh, acc[m], 0, 0, 0);
        }
    }

#pragma unroll
    for (int m = 0; m < 4; ++m) {
#pragma unroll
        for (int reg = 0; reg < 4; ++reg) {
            int b = m * 16 + kg * 4 + reg;
            part[(size_t)ks * 1310720 + ((size_t)(c * Bq + b) * NTq + r) * Sq + l] = acc[m][reg];
        }
    }
}

// ---------------- block reduce (256 threads)
__device__ __forceinline__ float block_reduce_sum(float v, float* red) {
#pragma unroll
    for (int o = 32; o > 0; o >>= 1) v += __shfl_xor(v, o, 64);
    int wid = threadIdx.x >> 6;
    if ((threadIdx.x & 63) == 0) red[wid] = v;
    __syncthreads();
    float r = red[0] + red[1] + red[2] + red[3];
    __syncthreads();
    return r;
}

// ---------------- Kernel 3: dynamic routing per (c,b). vote_out[c][b][l]
__global__ __launch_bounds__(256) void k3_route(const float* __restrict__ part,
                                                const int* __restrict__ task_p,
                                                float* __restrict__ vote_out) {
    __shared__ float pr[NTq][Sq];
    __shared__ float red[4];
    const int t = threadIdx.x;
    const int b = blockIdx.x & 63;
    const int c = blockIdx.x >> 6;
    const int task = *task_p;
    const size_t half = (size_t)CAPq * Bq * NTq * Sq;   // 1,310,720
    size_t base = ((size_t)(c*Bq + b) * NTq) * Sq;
#pragma unroll
    for (int r = 0; r < NTq; ++r)
        pr[r][t] = part[base + r*Sq + t] + part[half + base + r*Sq + t];
    __syncthreads();

    float logits[NTq];
#pragma unroll
    for (int r = 0; r < NTq; ++r) logits[r] = 0.f;
    float vote = 0.f;

    for (int it = 0; it < 3; ++it) {
        float m = -1e30f;
#pragma unroll
        for (int r = 0; r < NTq; ++r) if (r <= task) m = fmaxf(m, logits[r]);
        float p[NTq]; float s = 0.f;
#pragma unroll
        for (int r = 0; r < NTq; ++r) {
            p[r] = (r <= task) ? expf(logits[r] - m) : 0.f;
            s += p[r];
        }
        float inv = 1.f / s;
        vote = 0.f;
#pragma unroll
        for (int r = 0; r < NTq; ++r) vote = fmaf(p[r]*inv, pr[r][t], vote);
        if (it == 2) break;
        float sq = block_reduce_sum(vote*vote, red);
        float scale = (sq / (1.f + sq)) / sqrtf(sq);
        float outv = vote * scale;
#pragma unroll
        for (int r = 0; r < NTq; ++r) {
            float a = block_reduce_sum(pr[r][t] * outv, red);
            if (r <= task) logits[r] += a;
        }
    }
    vote_out[(size_t)(c*Bq + b)*Sq + t] = vote;
}

// ---------------- Kernel 4: h gather (flat reinterpret) + Linear(CAP->768)
__global__ __launch_bounds__(256) void k4_out(const float* __restrict__ vote, // [CAP][B][S] flat
                                              const float* __restrict__ lw,   // [768][8]
                                              const float* __restrict__ lb,   // [768]
                                              float* __restrict__ out) {      // [B,S,768]
    __shared__ float hS[8][8];
    const int t = threadIdx.x;
    if (t < 64) {
        int rr = t >> 3, cc = t & 7;
        size_t row = (size_t)blockIdx.x * 8 + rr;   // b'*256 + s'
        size_t flat = row * 8 + cc;                 // b'*2048 + s'*8 + c'
        int c = (int)(flat >> 14);                  // /16384
        int rem = (int)(flat & 16383);
        int bb = rem >> 8;
        int l = rem & 255;
        hS[rr][cc] = vote[(size_t)c*16384 + bb*256 + l];
    }
    float lwr[3][8];
    float lbr[3];
#pragma unroll
    for (int dd = 0; dd < 3; ++dd) {
        int d = t + dd*256;
        float4 a = *reinterpret_cast<const float4*>(&lw[(size_t)d*8]);
        float4 b2 = *reinterpret_cast<const float4*>(&lw[(size_t)d*8 + 4]);
        lwr[dd][0]=a.x; lwr[dd][1]=a.y; lwr[dd][2]=a.z; lwr[dd][3]=a.w;
        lwr[dd][4]=b2.x; lwr[dd][5]=b2.y; lwr[dd][6]=b2.z; lwr[dd][7]=b2.w;
        lbr[dd] = lb[d];
    }
    __syncthreads();
#pragma unroll
    for (int rr = 0; rr < 8; ++rr) {
        size_t row = (size_t)blockIdx.x * 8 + rr;
#pragma unroll
        for (int dd = 0; dd < 3; ++dd) {
            float acc = lbr[dd];
#pragma unroll
            for (int c = 0; c < 8; ++c) acc = fmaf(hS[rr][c], lwr[dd][c], acc);
            out[row*Dq + t + dd*256] = acc;
        }
    }
}

extern "C" void kernel_launch(void* const* d_in, const int* in_sizes, int n_in,
                              void* d_out, int out_size, void* d_ws, size_t ws_size,
                              hipStream_t stream) {
    const float* x    = (const float*)d_in[0];
    const int*   task = (const int*)d_in[1];
    const float* fc1w = (const float*)d_in[2];
    const float* fc1b = (const float*)d_in[3];
    const float* rw   = (const float*)d_in[4];
    const float* lw   = (const float*)d_in[5];
    const float* lb   = (const float*)d_in[6];
    float* out = (float*)d_out;

    short* u_hi = (short*)d_ws;                              // [64][10][2048] bf16 = 2,621,440 B
    short* u_lo = u_hi + 1310720;                            // same size
    float* part = (float*)((char*)d_ws + 5242880);           // [2][8][64][10][256] f32 = 10,485,760 B
    float* vote = part + 2621440;                            // [8][64][256] f32 = 524,288 B

    k1_sem<<<256, 256, 0, stream>>>(x, fc1w, fc1b, u_hi, u_lo);
    dim3 g2(8, NTq, CAPq);
    k2_priors<<<g2, 256, 0, stream>>>(u_hi, u_lo, rw, task, part);
    k3_route<<<512, 256, 0, stream>>>(part, task, vote);
    k4_out<<<2048, 256, 0, stream>>>(vote, lw, lb, out);
}

// Round 8
// 124.743 us; speedup vs baseline: 1.9637x; 1.4379x over previous
//
#include <hip/hip_runtime.h>
#include <hip/hip_bf16.h>

#define Bq 64
#define Sq 256
#define Dq 768
#define CAPq 8
#define NTq 10
#define SCq 2048   // S*CAP

typedef short bf16x8 __attribute__((ext_vector_type(8)));
typedef float f32x4  __attribute__((ext_vector_type(4)));

// split f32 into hi/lo bf16 (bit-truncation; f ~= hi + lo, residual ~2^-17 |f|)
static __device__ __forceinline__ short bfhi(float f) {
    return (short)(__float_as_uint(f) >> 16);
}
static __device__ __forceinline__ short bflo(float f) {
    float hi = __uint_as_float(__float_as_uint(f) & 0xFFFF0000u);
    return (short)(__float_as_uint(f - hi) >> 16);
}

// ---------------- Kernel 0: preconvert fc1w (80x768 f32) -> hi/lo bf16
__global__ __launch_bounds__(256) void k0_cvt(const float* __restrict__ w,
                                              short* __restrict__ hi,
                                              short* __restrict__ lo) {
    int i = blockIdx.x * 256 + threadIdx.x;
    if (i < NTq * CAPq * Dq) {
        float f = w[i];
        hi[i] = bfhi(f);
        lo[i] = bflo(f);
    }
}

// ---------------- Kernel 1 (split-bf16 MFMA): sem = x·fc1w^T + b, squash over routes,
// write u as hi/lo bf16 pair, layout [B][NT][S*CAP].
// Block: 64 rows, 4 waves x 16 rows. N=80 = 5 frags. K=768, prefetched x stream.
__global__ __launch_bounds__(256, 2) void k1_sem(const float* __restrict__ x,
                                                 const short* __restrict__ fwh,
                                                 const short* __restrict__ fwl,
                                                 const float* __restrict__ fc1b,
                                                 short* __restrict__ u_hi,
                                                 short* __restrict__ u_lo) {
    const int t = threadIdx.x;
    const int L = t & 63, w = t >> 6;
    const int colL = L & 15, kg = L >> 4;
    const int R0 = blockIdx.x * 64;
    const int rowA = R0 + w * 16 + colL;

    float bias[5];
#pragma unroll
    for (int f = 0; f < 5; ++f) bias[f] = fc1b[f * 16 + colL];

    f32x4 acc[5];
#pragma unroll
    for (int f = 0; f < 5; ++f) acc[f] = (f32x4){0.f, 0.f, 0.f, 0.f};

    const float* px = x + (size_t)rowA * Dq + kg * 8;
    const short* pwh = fwh + (size_t)colL * Dq + kg * 8;
    const short* pwl = fwl + (size_t)colL * Dq + kg * 8;

    float xv0[8], xv1[8];
#pragma unroll
    for (int i = 0; i < 8; ++i) xv0[i] = px[i];

    for (int kc = 0; kc < Dq; kc += 64) {
        // prefetch x chunk kc+32
        {
            const float* p = px + kc + 32;
#pragma unroll
            for (int i = 0; i < 8; ++i) xv1[i] = p[i];
        }
        // compute chunk kc
        {
            bf16x8 ah, al;
#pragma unroll
            for (int i = 0; i < 8; ++i) { ah[i] = bfhi(xv0[i]); al[i] = bflo(xv0[i]); }
            bf16x8 bh[5], bl[5];
#pragma unroll
            for (int f = 0; f < 5; ++f) {
                bh[f] = *reinterpret_cast<const bf16x8*>(pwh + (size_t)(f * 16) * Dq + kc);
                bl[f] = *reinterpret_cast<const bf16x8*>(pwl + (size_t)(f * 16) * Dq + kc);
            }
#pragma unroll
            for (int f = 0; f < 5; ++f) {
                acc[f] = __builtin_amdgcn_mfma_f32_16x16x32_bf16(al, bh[f], acc[f], 0, 0, 0);
                acc[f] = __builtin_amdgcn_mfma_f32_16x16x32_bf16(ah, bl[f], acc[f], 0, 0, 0);
                acc[f] = __builtin_amdgcn_mfma_f32_16x16x32_bf16(ah, bh[f], acc[f], 0, 0, 0);
            }
        }
        // prefetch x chunk kc+64 (dummy 0 on last iter)
        {
            int kn = (kc + 64 < Dq) ? kc + 64 : 0;
            const float* p = px + kn;
#pragma unroll
            for (int i = 0; i < 8; ++i) xv0[i] = p[i];
        }
        // compute chunk kc+32
        {
            bf16x8 ah, al;
#pragma unroll
            for (int i = 0; i < 8; ++i) { ah[i] = bfhi(xv1[i]); al[i] = bflo(xv1[i]); }
            bf16x8 bh[5], bl[5];
#pragma unroll
            for (int f = 0; f < 5; ++f) {
                bh[f] = *reinterpret_cast<const bf16x8*>(pwh + (size_t)(f * 16) * Dq + kc + 32);
                bl[f] = *reinterpret_cast<const bf16x8*>(pwl + (size_t)(f * 16) * Dq + kc + 32);
            }
#pragma unroll
            for (int f = 0; f < 5; ++f) {
                acc[f] = __builtin_amdgcn_mfma_f32_16x16x32_bf16(al, bh[f], acc[f], 0, 0, 0);
                acc[f] = __builtin_amdgcn_mfma_f32_16x16x32_bf16(ah, bl[f], acc[f], 0, 0, 0);
                acc[f] = __builtin_amdgcn_mfma_f32_16x16x32_bf16(ah, bh[f], acc[f], 0, 0, 0);
            }
        }
    }

    // epilogue: bias + squash over the 10 routes of each (row, capsule)
    const int cc = colL & 7;
    const int npar = (colL >> 3) & 1;
#pragma unroll
    for (int reg = 0; reg < 4; ++reg) {
        const int row = R0 + w * 16 + kg * 4 + reg;    // C/D: row=(L>>4)*4+reg
        const int b = row >> 8, s = row & 255;
        float v[5], sqp = 0.f;
#pragma unroll
        for (int f = 0; f < 5; ++f) {
            v[f] = acc[f][reg] + bias[f];
            sqp = fmaf(v[f], v[f], sqp);
        }
        float sq = sqp + __shfl_xor(sqp, 8, 64);       // pair even/odd routes (colL ^ 8)
        float scale = (sq / (1.f + sq)) / sqrtf(sq);
#pragma unroll
        for (int f = 0; f < 5; ++f) {
            int n = 2 * f + npar;
            size_t off = ((size_t)b * NTq + n) * SCq + s * 8 + cc;
            float val = v[f] * scale;
            u_hi[off] = bfhi(val);
            u_lo[off] = bflo(val);
        }
    }
}

// ---------------- Kernel 2 (split-bf16 MFMA, prefetched, LDS k-reduce):
// part[ks][c][b][r][l] = sum_{k in half ks} u[b,r,k]*rw[c,r,k,l]
// grid.x: lq = x&7 (32-l chunk), ks = x>>3 (1024-k half); y=r, z=c.
// Waves: lh = w&1 (16-l), kh = w>>1 (512-k sub-half); cross-kh reduced in LDS.
__global__ __launch_bounds__(256, 3) void k2_priors(const short* __restrict__ u_hi,
                                                    const short* __restrict__ u_lo,
                                                    const float* __restrict__ rw,
                                                    const int* __restrict__ task_p,
                                                    float* __restrict__ part) {
    const int r = blockIdx.y;
    if (r > *task_p) return;
    __shared__ float redS[2][16][64];
    const int t = threadIdx.x;
    const int L = t & 63, w = t >> 6;
    const int colL = L & 15, kg = L >> 4;
    const int lq = blockIdx.x & 7, ks = blockIdx.x >> 3;
    const int c = blockIdx.z;
    const int lh = w & 1, kh = w >> 1;
    const int l = lq * 32 + lh * 16 + colL;
    const int kw0 = ks * 1024 + kh * 512;

    f32x4 acc[4];
#pragma unroll
    for (int m = 0; m < 4; ++m) acc[m] = (f32x4){0.f, 0.f, 0.f, 0.f};

    const float* pb = rw + ((size_t)(c * NTq + r) * SCq + kw0 + kg * 8) * Sq + l;
    const short* puh = u_hi + ((size_t)colL * NTq + r) * SCq + kw0 + kg * 8;
    const short* pul = u_lo + ((size_t)colL * NTq + r) * SCq + kw0 + kg * 8;

    float bv0[8], bv1[8];
    bf16x8 ah0[4], al0[4], ah1[4], al1[4];

    // prologue: load chunk 0 into slot0
#pragma unroll
    for (int i = 0; i < 8; ++i) bv0[i] = pb[(size_t)i * Sq];
#pragma unroll
    for (int m = 0; m < 4; ++m) {
        ah0[m] = *reinterpret_cast<const bf16x8*>(puh + (size_t)(16 * m) * (NTq * SCq));
        al0[m] = *reinterpret_cast<const bf16x8*>(pul + (size_t)(16 * m) * (NTq * SCq));
    }

    for (int kc = 0; kc < 512; kc += 64) {
        // prefetch chunk kc+32 into slot1
        {
            const float* p = pb + (size_t)(kc + 32) * Sq;
#pragma unroll
            for (int i = 0; i < 8; ++i) bv1[i] = p[(size_t)i * Sq];
#pragma unroll
            for (int m = 0; m < 4; ++m) {
                ah1[m] = *reinterpret_cast<const bf16x8*>(puh + (size_t)(16 * m) * (NTq * SCq) + kc + 32);
                al1[m] = *reinterpret_cast<const bf16x8*>(pul + (size_t)(16 * m) * (NTq * SCq) + kc + 32);
            }
        }
        // compute slot0 (chunk kc)
        {
            bf16x8 bh, bl;
#pragma unroll
            for (int i = 0; i < 8; ++i) { bh[i] = bfhi(bv0[i]); bl[i] = bflo(bv0[i]); }
#pragma unroll
            for (int m = 0; m < 4; ++m) {
                acc[m] = __builtin_amdgcn_mfma_f32_16x16x32_bf16(al0[m], bh, acc[m], 0, 0, 0);
                acc[m] = __builtin_amdgcn_mfma_f32_16x16x32_bf16(ah0[m], bl, acc[m], 0, 0, 0);
                acc[m] = __builtin_amdgcn_mfma_f32_16x16x32_bf16(ah0[m], bh, acc[m], 0, 0, 0);
            }
        }
        // prefetch chunk kc+64 into slot0 (dummy 0 on last iter)
        {
            int kn = (kc + 64 < 512) ? kc + 64 : 0;
            const float* p = pb + (size_t)kn * Sq;
#pragma unroll
            for (int i = 0; i < 8; ++i) bv0[i] = p[(size_t)i * Sq];
#pragma unroll
            for (int m = 0; m < 4; ++m) {
                ah0[m] = *reinterpret_cast<const bf16x8*>(puh + (size_t)(16 * m) * (NTq * SCq) + kn);
                al0[m] = *reinterpret_cast<const bf16x8*>(pul + (size_t)(16 * m) * (NTq * SCq) + kn);
            }
        }
        // compute slot1 (chunk kc+32)
        {
            bf16x8 bh, bl;
#pragma unroll
            for (int i = 0; i < 8; ++i) { bh[i] = bfhi(bv1[i]); bl[i] = bflo(bv1[i]); }
#pragma unroll
            for (int m = 0; m < 4; ++m) {
                acc[m] = __builtin_amdgcn_mfma_f32_16x16x32_bf16(al1[m], bh, acc[m], 0, 0, 0);
                acc[m] = __builtin_amdgcn_mfma_f32_16x16x32_bf16(ah1[m], bl, acc[m], 0, 0, 0);
                acc[m] = __builtin_amdgcn_mfma_f32_16x16x32_bf16(ah1[m], bh, acc[m], 0, 0, 0);
            }
        }
    }

    // cross-kh reduction in LDS; kh==0 waves write out
    if (kh == 1) {
#pragma unroll
        for (int m = 0; m < 4; ++m)
#pragma unroll
            for (int g = 0; g < 4; ++g)
                redS[lh][m * 4 + g][L] = acc[m][g];
    }
    __syncthreads();
    if (kh == 0) {
#pragma unroll
        for (int m = 0; m < 4; ++m) {
#pragma unroll
            for (int g = 0; g < 4; ++g) {
                float v = acc[m][g] + redS[lh][m * 4 + g][L];
                int b = m * 16 + kg * 4 + g;
                part[(size_t)ks * 1310720 + ((size_t)(c * Bq + b) * NTq + r) * Sq + l] = v;
            }
        }
    }
}

// ---------------- block reduce (256 threads)
__device__ __forceinline__ float block_reduce_sum(float v, float* red) {
#pragma unroll
    for (int o = 32; o > 0; o >>= 1) v += __shfl_xor(v, o, 64);
    int wid = threadIdx.x >> 6;
    if ((threadIdx.x & 63) == 0) red[wid] = v;
    __syncthreads();
    float r = red[0] + red[1] + red[2] + red[3];
    __syncthreads();
    return r;
}

// ---------------- Kernel 3: dynamic routing per (c,b). vote_out[c][b][l]
__global__ __launch_bounds__(256) void k3_route(const float* __restrict__ part,
                                                const int* __restrict__ task_p,
                                                float* __restrict__ vote_out) {
    __shared__ float pr[NTq][Sq];
    __shared__ float red[4];
    const int t = threadIdx.x;
    const int b = blockIdx.x & 63;
    const int c = blockIdx.x >> 6;
    const int task = *task_p;
    const size_t half = (size_t)CAPq * Bq * NTq * Sq;   // 1,310,720
    size_t base = ((size_t)(c*Bq + b) * NTq) * Sq;
#pragma unroll
    for (int r = 0; r < NTq; ++r)
        pr[r][t] = part[base + r*Sq + t] + part[half + base + r*Sq + t];
    __syncthreads();

    float logits[NTq];
#pragma unroll
    for (int r = 0; r < NTq; ++r) logits[r] = 0.f;
    float vote = 0.f;

    for (int it = 0; it < 3; ++it) {
        float m = -1e30f;
#pragma unroll
        for (int r = 0; r < NTq; ++r) if (r <= task) m = fmaxf(m, logits[r]);
        float p[NTq]; float s = 0.f;
#pragma unroll
        for (int r = 0; r < NTq; ++r) {
            p[r] = (r <= task) ? expf(logits[r] - m) : 0.f;
            s += p[r];
        }
        float inv = 1.f / s;
        vote = 0.f;
#pragma unroll
        for (int r = 0; r < NTq; ++r) vote = fmaf(p[r]*inv, pr[r][t], vote);
        if (it == 2) break;
        float sq = block_reduce_sum(vote*vote, red);
        float scale = (sq / (1.f + sq)) / sqrtf(sq);
        float outv = vote * scale;
#pragma unroll
        for (int r = 0; r < NTq; ++r) {
            float a = block_reduce_sum(pr[r][t] * outv, red);
            if (r <= task) logits[r] += a;
        }
    }
    vote_out[(size_t)(c*Bq + b)*Sq + t] = vote;
}

// ---------------- Kernel 4: h gather (flat reinterpret) + Linear(CAP->768)
__global__ __launch_bounds__(256) void k4_out(const float* __restrict__ vote, // [CAP][B][S] flat
                                              const float* __restrict__ lw,   // [768][8]
                                              const float* __restrict__ lb,   // [768]
                                              float* __restrict__ out) {      // [B,S,768]
    __shared__ float hS[8][8];
    const int t = threadIdx.x;
    if (t < 64) {
        int rr = t >> 3, cc = t & 7;
        size_t row = (size_t)blockIdx.x * 8 + rr;   // b'*256 + s'
        size_t flat = row * 8 + cc;                 // b'*2048 + s'*8 + c'
        int c = (int)(flat >> 14);                  // /16384
        int rem = (int)(flat & 16383);
        int bb = rem >> 8;
        int l = rem & 255;
        hS[rr][cc] = vote[(size_t)c*16384 + bb*256 + l];
    }
    float lwr[3][8];
    float lbr[3];
#pragma unroll
    for (int dd = 0; dd < 3; ++dd) {
        int d = t + dd*256;
        float4 a = *reinterpret_cast<const float4*>(&lw[(size_t)d*8]);
        float4 b2 = *reinterpret_cast<const float4*>(&lw[(size_t)d*8 + 4]);
        lwr[dd][0]=a.x; lwr[dd][1]=a.y; lwr[dd][2]=a.z; lwr[dd][3]=a.w;
        lwr[dd][4]=b2.x; lwr[dd][5]=b2.y; lwr[dd][6]=b2.z; lwr[dd][7]=b2.w;
        lbr[dd] = lb[d];
    }
    __syncthreads();
#pragma unroll
    for (int rr = 0; rr < 8; ++rr) {
        size_t row = (size_t)blockIdx.x * 8 + rr;
#pragma unroll
        for (int dd = 0; dd < 3; ++dd) {
            float acc = lbr[dd];
#pragma unroll
            for (int c = 0; c < 8; ++c) acc = fmaf(hS[rr][c], lwr[dd][c], acc);
            out[row*Dq + t + dd*256] = acc;
        }
    }
}

extern "C" void kernel_launch(void* const* d_in, const int* in_sizes, int n_in,
                              void* d_out, int out_size, void* d_ws, size_t ws_size,
                              hipStream_t stream) {
    const float* x    = (const float*)d_in[0];
    const int*   task = (const int*)d_in[1];
    const float* fc1w = (const float*)d_in[2];
    const float* fc1b = (const float*)d_in[3];
    const float* rw   = (const float*)d_in[4];
    const float* lw   = (const float*)d_in[5];
    const float* lb   = (const float*)d_in[6];
    float* out = (float*)d_out;

    short* u_hi = (short*)d_ws;                              // 2,621,440 B
    short* u_lo = u_hi + 1310720;                            // 2,621,440 B
    float* part = (float*)((char*)d_ws + 5242880);           // 10,485,760 B
    float* vote = part + 2621440;                            // 524,288 B
    short* fwh  = (short*)((char*)d_ws + 16252928);          // 122,880 B
    short* fwl  = fwh + 61440;                               // 122,880 B

    k0_cvt<<<240, 256, 0, stream>>>(fc1w, fwh, fwl);
    k1_sem<<<256, 256, 0, stream>>>(x, fwh, fwl, fc1b, u_hi, u_lo);
    dim3 g2(16, NTq, CAPq);
    k2_priors<<<g2, 256, 0, stream>>>(u_hi, u_lo, rw, task, part);
    k3_route<<<512, 256, 0, stream>>>(part, task, vote);
    k4_out<<<2048, 256, 0, stream>>>(vote, lw, lb, out);
}

// Round 9
// 115.696 us; speedup vs baseline: 2.1172x; 1.0782x over previous
//
#include <hip/hip_runtime.h>
#include <hip/hip_bf16.h>

#define Bq 64
#define Sq 256
#define Dq 768
#define CAPq 8
#define NTq 10
#define SCq 2048   // S*CAP

typedef short bf16x8 __attribute__((ext_vector_type(8)));
typedef float f32x4  __attribute__((ext_vector_type(4)));

// split f32 into hi/lo bf16 (bit-truncation; f ~= hi + lo, residual ~2^-17 |f|)
static __device__ __forceinline__ short bfhi(float f) {
    return (short)(__float_as_uint(f) >> 16);
}
static __device__ __forceinline__ short bflo(float f) {
    float hi = __uint_as_float(__float_as_uint(f) & 0xFFFF0000u);
    return (short)(__float_as_uint(f - hi) >> 16);
}

// ---------------- Kernel 0: preconvert fc1w (80x768 f32, [n*8+c][k]) into
// fragment-major hi/lo bf16: fw2[k/8][col=80][8], col = n*8+c.
__global__ __launch_bounds__(256) void k0_cvt(const float* __restrict__ w,
                                              short* __restrict__ hi,
                                              short* __restrict__ lo) {
    int i = blockIdx.x * 256 + threadIdx.x;   // output index
    if (i < NTq * CAPq * Dq) {
        int k8 = i / 640;
        int rem = i - k8 * 640;
        int o = rem >> 3, kf = rem & 7;
        float f = w[o * Dq + k8 * 8 + kf];
        hi[i] = bfhi(f);
        lo[i] = bflo(f);
    }
}

// ---------------- Kernel 1 (split-bf16 MFMA): sem = x·fc1w^T + b, squash over routes,
// write u2 hi/lo bf16, layout [n][s][b][c]  (k2's A-operand: 8 consecutive k = one s-group).
// Block: 64 rows, 4 waves x 16 rows. N=80 = 5 frags. K=768, prefetched x stream.
__global__ __launch_bounds__(256, 2) void k1_sem(const float* __restrict__ x,
                                                 const short* __restrict__ fwh,
                                                 const short* __restrict__ fwl,
                                                 const float* __restrict__ fc1b,
                                                 short* __restrict__ u_hi,
                                                 short* __restrict__ u_lo) {
    const int t = threadIdx.x;
    const int L = t & 63, w = t >> 6;
    const int colL = L & 15, kg = L >> 4;
    const int R0 = blockIdx.x * 64;
    const int rowA = R0 + w * 16 + colL;

    float bias[5];
#pragma unroll
    for (int f = 0; f < 5; ++f) bias[f] = fc1b[f * 16 + colL];

    f32x4 acc[5];
#pragma unroll
    for (int f = 0; f < 5; ++f) acc[f] = (f32x4){0.f, 0.f, 0.f, 0.f};

    const float* px = x + (size_t)rowA * Dq + kg * 8;
    // fw2 fragment base for this lane: (kg*80 + colL)*8; per kc: +kc*80; per f: +128
    const short* pwh = fwh + ((size_t)kg * 80 + colL) * 8;
    const short* pwl = fwl + ((size_t)kg * 80 + colL) * 8;

    float xv0[8], xv1[8];
#pragma unroll
    for (int i = 0; i < 8; ++i) xv0[i] = px[i];

    for (int kc = 0; kc < Dq; kc += 64) {
        // prefetch x chunk kc+32
        {
            const float* p = px + kc + 32;
#pragma unroll
            for (int i = 0; i < 8; ++i) xv1[i] = p[i];
        }
        // compute chunk kc
        {
            bf16x8 ah, al;
#pragma unroll
            for (int i = 0; i < 8; ++i) { ah[i] = bfhi(xv0[i]); al[i] = bflo(xv0[i]); }
#pragma unroll
            for (int f = 0; f < 5; ++f) {
                bf16x8 bh = *reinterpret_cast<const bf16x8*>(pwh + (size_t)kc * 80 + f * 128);
                bf16x8 bl = *reinterpret_cast<const bf16x8*>(pwl + (size_t)kc * 80 + f * 128);
                acc[f] = __builtin_amdgcn_mfma_f32_16x16x32_bf16(al, bh, acc[f], 0, 0, 0);
                acc[f] = __builtin_amdgcn_mfma_f32_16x16x32_bf16(ah, bl, acc[f], 0, 0, 0);
                acc[f] = __builtin_amdgcn_mfma_f32_16x16x32_bf16(ah, bh, acc[f], 0, 0, 0);
            }
        }
        // prefetch x chunk kc+64 (dummy 0 on last iter)
        {
            int kn = (kc + 64 < Dq) ? kc + 64 : 0;
            const float* p = px + kn;
#pragma unroll
            for (int i = 0; i < 8; ++i) xv0[i] = p[i];
        }
        // compute chunk kc+32
        {
            bf16x8 ah, al;
#pragma unroll
            for (int i = 0; i < 8; ++i) { ah[i] = bfhi(xv1[i]); al[i] = bflo(xv1[i]); }
#pragma unroll
            for (int f = 0; f < 5; ++f) {
                bf16x8 bh = *reinterpret_cast<const bf16x8*>(pwh + (size_t)(kc + 32) * 80 + f * 128);
                bf16x8 bl = *reinterpret_cast<const bf16x8*>(pwl + (size_t)(kc + 32) * 80 + f * 128);
                acc[f] = __builtin_amdgcn_mfma_f32_16x16x32_bf16(al, bh, acc[f], 0, 0, 0);
                acc[f] = __builtin_amdgcn_mfma_f32_16x16x32_bf16(ah, bl, acc[f], 0, 0, 0);
                acc[f] = __builtin_amdgcn_mfma_f32_16x16x32_bf16(ah, bh, acc[f], 0, 0, 0);
            }
        }
    }

    // epilogue: bias + squash over the 10 routes of each (row, capsule)
    const int cc = colL & 7;
    const int npar = (colL >> 3) & 1;
#pragma unroll
    for (int reg = 0; reg < 4; ++reg) {
        const int row = R0 + w * 16 + kg * 4 + reg;    // C/D: row=(L>>4)*4+reg
        const int b = row >> 8, s = row & 255;
        float v[5], sqp = 0.f;
#pragma unroll
        for (int f = 0; f < 5; ++f) {
            v[f] = acc[f][reg] + bias[f];
            sqp = fmaf(v[f], v[f], sqp);
        }
        float sq = sqp + __shfl_xor(sqp, 8, 64);       // pair even/odd routes (colL ^ 8)
        float scale = (sq / (1.f + sq)) / sqrtf(sq);
#pragma unroll
        for (int f = 0; f < 5; ++f) {
            int n = 2 * f + npar;
            size_t off = (((size_t)n * 256 + s) * 64 + b) * 8 + cc;   // u2[n][s][b][c]
            float val = v[f] * scale;
            u_hi[off] = bfhi(val);
            u_lo[off] = bflo(val);
        }
    }
}

// ---------------- Kernel 2 (split-bf16 MFMA, prefetched, LDS k-reduce):
// part[ks][c][b][r][l] = sum_{k in half ks} u[b,r,k]*rw[c,r,k,l]
// u2 layout [r][s][b][c] makes A-loads 4x256B-segment coalesced.
// grid.x: lq = x&7 (32-l chunk), ks = x>>3 (1024-k half); y=r, z=c.
// Waves: lh = w&1 (16-l), kh = w>>1 (512-k sub-half); cross-kh reduced in LDS.
__global__ __launch_bounds__(256, 3) void k2_priors(const short* __restrict__ u_hi,
                                                    const short* __restrict__ u_lo,
                                                    const float* __restrict__ rw,
                                                    const int* __restrict__ task_p,
                                                    float* __restrict__ part) {
    const int r = blockIdx.y;
    if (r > *task_p) return;
    __shared__ float redS[2][16][64];
    const int t = threadIdx.x;
    const int L = t & 63, w = t >> 6;
    const int colL = L & 15, kg = L >> 4;
    const int lq = blockIdx.x & 7, ks = blockIdx.x >> 3;
    const int c = blockIdx.z;
    const int lh = w & 1, kh = w >> 1;
    const int l = lq * 32 + lh * 16 + colL;
    const int kw0 = ks * 1024 + kh * 512;
    const int s00 = kw0 >> 3;                    // starting s; chunk kc -> s = s00 + kc/8 + kg

    f32x4 acc[4];
#pragma unroll
    for (int m = 0; m < 4; ++m) acc[m] = (f32x4){0.f, 0.f, 0.f, 0.f};

    const float* pb = rw + ((size_t)(c * NTq + r) * SCq + kw0 + kg * 8) * Sq + l;
    // A base: u2[r][s00+kg][colL][0]; per kc: +kc*64 elems; per m: +128 elems
    const short* puh = u_hi + (((size_t)r * 256 + s00 + kg) * 64 + colL) * 8;
    const short* pul = u_lo + (((size_t)r * 256 + s00 + kg) * 64 + colL) * 8;

    float bv0[8], bv1[8];
    bf16x8 ah0[4], al0[4], ah1[4], al1[4];

    // prologue: load chunk 0 into slot0
#pragma unroll
    for (int i = 0; i < 8; ++i) bv0[i] = pb[(size_t)i * Sq];
#pragma unroll
    for (int m = 0; m < 4; ++m) {
        ah0[m] = *reinterpret_cast<const bf16x8*>(puh + m * 128);
        al0[m] = *reinterpret_cast<const bf16x8*>(pul + m * 128);
    }

    for (int kc = 0; kc < 512; kc += 64) {
        // prefetch chunk kc+32 into slot1
        {
            const float* p = pb + (size_t)(kc + 32) * Sq;
            const size_t ao = (size_t)(kc + 32) * 64;
#pragma unroll
            for (int i = 0; i < 8; ++i) bv1[i] = p[(size_t)i * Sq];
#pragma unroll
            for (int m = 0; m < 4; ++m) {
                ah1[m] = *reinterpret_cast<const bf16x8*>(puh + ao + m * 128);
                al1[m] = *reinterpret_cast<const bf16x8*>(pul + ao + m * 128);
            }
        }
        // compute slot0 (chunk kc)
        {
            bf16x8 bh, bl;
#pragma unroll
            for (int i = 0; i < 8; ++i) { bh[i] = bfhi(bv0[i]); bl[i] = bflo(bv0[i]); }
#pragma unroll
            for (int m = 0; m < 4; ++m) {
                acc[m] = __builtin_amdgcn_mfma_f32_16x16x32_bf16(al0[m], bh, acc[m], 0, 0, 0);
                acc[m] = __builtin_amdgcn_mfma_f32_16x16x32_bf16(ah0[m], bl, acc[m], 0, 0, 0);
                acc[m] = __builtin_amdgcn_mfma_f32_16x16x32_bf16(ah0[m], bh, acc[m], 0, 0, 0);
            }
        }
        // prefetch chunk kc+64 into slot0 (dummy 0 on last iter)
        {
            int kn = (kc + 64 < 512) ? kc + 64 : 0;
            const float* p = pb + (size_t)kn * Sq;
            const size_t ao = (size_t)kn * 64;
#pragma unroll
            for (int i = 0; i < 8; ++i) bv0[i] = p[(size_t)i * Sq];
#pragma unroll
            for (int m = 0; m < 4; ++m) {
                ah0[m] = *reinterpret_cast<const bf16x8*>(puh + ao + m * 128);
                al0[m] = *reinterpret_cast<const bf16x8*>(pul + ao + m * 128);
            }
        }
        // compute slot1 (chunk kc+32)
        {
            bf16x8 bh, bl;
#pragma unroll
            for (int i = 0; i < 8; ++i) { bh[i] = bfhi(bv1[i]); bl[i] = bflo(bv1[i]); }
#pragma unroll
            for (int m = 0; m < 4; ++m) {
                acc[m] = __builtin_amdgcn_mfma_f32_16x16x32_bf16(al1[m], bh, acc[m], 0, 0, 0);
                acc[m] = __builtin_amdgcn_mfma_f32_16x16x32_bf16(ah1[m], bl, acc[m], 0, 0, 0);
                acc[m] = __builtin_amdgcn_mfma_f32_16x16x32_bf16(ah1[m], bh, acc[m], 0, 0, 0);
            }
        }
    }

    // cross-kh reduction in LDS; kh==0 waves write out
    if (kh == 1) {
#pragma unroll
        for (int m = 0; m < 4; ++m)
#pragma unroll
            for (int g = 0; g < 4; ++g)
                redS[lh][m * 4 + g][L] = acc[m][g];
    }
    __syncthreads();
    if (kh == 0) {
#pragma unroll
        for (int m = 0; m < 4; ++m) {
#pragma unroll
            for (int g = 0; g < 4; ++g) {
                float v = acc[m][g] + redS[lh][m * 4 + g][L];
                int b = m * 16 + kg * 4 + g;
                part[(size_t)ks * 1310720 + ((size_t)(c * Bq + b) * NTq + r) * Sq + l] = v;
            }
        }
    }
}

// ---------------- block reduce (256 threads)
__device__ __forceinline__ float block_reduce_sum(float v, float* red) {
#pragma unroll
    for (int o = 32; o > 0; o >>= 1) v += __shfl_xor(v, o, 64);
    int wid = threadIdx.x >> 6;
    if ((threadIdx.x & 63) == 0) red[wid] = v;
    __syncthreads();
    float r = red[0] + red[1] + red[2] + red[3];
    __syncthreads();
    return r;
}

// ---------------- Kernel 3: dynamic routing per (c,b). vote_out[c][b][l]
__global__ __launch_bounds__(256) void k3_route(const float* __restrict__ part,
                                                const int* __restrict__ task_p,
                                                float* __restrict__ vote_out) {
    __shared__ float pr[NTq][Sq];
    __shared__ float red[4];
    const int t = threadIdx.x;
    const int b = blockIdx.x & 63;
    const int c = blockIdx.x >> 6;
    const int task = *task_p;
    const size_t half = (size_t)CAPq * Bq * NTq * Sq;   // 1,310,720
    size_t base = ((size_t)(c*Bq + b) * NTq) * Sq;
#pragma unroll
    for (int r = 0; r < NTq; ++r)
        pr[r][t] = part[base + r*Sq + t] + part[half + base + r*Sq + t];
    __syncthreads();

    float logits[NTq];
#pragma unroll
    for (int r = 0; r < NTq; ++r) logits[r] = 0.f;
    float vote = 0.f;

    for (int it = 0; it < 3; ++it) {
        float m = -1e30f;
#pragma unroll
        for (int r = 0; r < NTq; ++r) if (r <= task) m = fmaxf(m, logits[r]);
        float p[NTq]; float s = 0.f;
#pragma unroll
        for (int r = 0; r < NTq; ++r) {
            p[r] = (r <= task) ? expf(logits[r] - m) : 0.f;
            s += p[r];
        }
        float inv = 1.f / s;
        vote = 0.f;
#pragma unroll
        for (int r = 0; r < NTq; ++r) vote = fmaf(p[r]*inv, pr[r][t], vote);
        if (it == 2) break;
        float sq = block_reduce_sum(vote*vote, red);
        float scale = (sq / (1.f + sq)) / sqrtf(sq);
        float outv = vote * scale;
#pragma unroll
        for (int r = 0; r < NTq; ++r) {
            float a = block_reduce_sum(pr[r][t] * outv, red);
            if (r <= task) logits[r] += a;
        }
    }
    vote_out[(size_t)(c*Bq + b)*Sq + t] = vote;
}

// ---------------- Kernel 4: h gather (flat reinterpret) + Linear(CAP->768)
__global__ __launch_bounds__(256) void k4_out(const float* __restrict__ vote, // [CAP][B][S] flat
                                              const float* __restrict__ lw,   // [768][8]
                                              const float* __restrict__ lb,   // [768]
                                              float* __restrict__ out) {      // [B,S,768]
    __shared__ float hS[8][8];
    const int t = threadIdx.x;
    if (t < 64) {
        int rr = t >> 3, cc = t & 7;
        size_t row = (size_t)blockIdx.x * 8 + rr;   // b'*256 + s'
        size_t flat = row * 8 + cc;                 // b'*2048 + s'*8 + c'
        int c = (int)(flat >> 14);                  // /16384
        int rem = (int)(flat & 16383);
        int bb = rem >> 8;
        int l = rem & 255;
        hS[rr][cc] = vote[(size_t)c*16384 + bb*256 + l];
    }
    float lwr[3][8];
    float lbr[3];
#pragma unroll
    for (int dd = 0; dd < 3; ++dd) {
        int d = t + dd*256;
        float4 a = *reinterpret_cast<const float4*>(&lw[(size_t)d*8]);
        float4 b2 = *reinterpret_cast<const float4*>(&lw[(size_t)d*8 + 4]);
        lwr[dd][0]=a.x; lwr[dd][1]=a.y; lwr[dd][2]=a.z; lwr[dd][3]=a.w;
        lwr[dd][4]=b2.x; lwr[dd][5]=b2.y; lwr[dd][6]=b2.z; lwr[dd][7]=b2.w;
        lbr[dd] = lb[d];
    }
    __syncthreads();
#pragma unroll
    for (int rr = 0; rr < 8; ++rr) {
        size_t row = (size_t)blockIdx.x * 8 + rr;
#pragma unroll
        for (int dd = 0; dd < 3; ++dd) {
            float acc = lbr[dd];
#pragma unroll
            for (int c = 0; c < 8; ++c) acc = fmaf(hS[rr][c], lwr[dd][c], acc);
            out[row*Dq + t + dd*256] = acc;
        }
    }
}

extern "C" void kernel_launch(void* const* d_in, const int* in_sizes, int n_in,
                              void* d_out, int out_size, void* d_ws, size_t ws_size,
                              hipStream_t stream) {
    const float* x    = (const float*)d_in[0];
    const int*   task = (const int*)d_in[1];
    const float* fc1w = (const float*)d_in[2];
    const float* fc1b = (const float*)d_in[3];
    const float* rw   = (const float*)d_in[4];
    const float* lw   = (const float*)d_in[5];
    const float* lb   = (const float*)d_in[6];
    float* out = (float*)d_out;

    short* u_hi = (short*)d_ws;                              // 2,621,440 B
    short* u_lo = u_hi + 1310720;                            // 2,621,440 B
    float* part = (float*)((char*)d_ws + 5242880);           // 10,485,760 B
    float* vote = part + 2621440;                            // 524,288 B
    short* fwh  = (short*)((char*)d_ws + 16252928);          // 122,880 B
    short* fwl  = fwh + 61440;                               // 122,880 B

    k0_cvt<<<240, 256, 0, stream>>>(fc1w, fwh, fwl);
    k1_sem<<<256, 256, 0, stream>>>(x, fwh, fwl, fc1b, u_hi, u_lo);
    dim3 g2(16, NTq, CAPq);
    k2_priors<<<g2, 256, 0, stream>>>(u_hi, u_lo, rw, task, part);
    k3_route<<<512, 256, 0, stream>>>(part, task, vote);
    k4_out<<<2048, 256, 0, stream>>>(vote, lw, lb, out);
}

// Round 10
// 78.057 us; speedup vs baseline: 3.1382x; 1.4822x over previous
//
#include <hip/hip_runtime.h>
#include <hip/hip_bf16.h>

#define Bq 64
#define Sq 256
#define Dq 768
#define CAPq 8
#define NTq 10
#define SCq 2048   // S*CAP

typedef short bf16x8 __attribute__((ext_vector_type(8)));
typedef float f32x4  __attribute__((ext_vector_type(4)));

// split f32 into hi/lo bf16 (bit-truncation; f ~= hi + lo, residual ~2^-17 |f|)
static __device__ __forceinline__ short bfhi(float f) {
    return (short)(__float_as_uint(f) >> 16);
}
static __device__ __forceinline__ short bflo(float f) {
    float hi = __uint_as_float(__float_as_uint(f) & 0xFFFF0000u);
    return (short)(__float_as_uint(f - hi) >> 16);
}

// ---------------- Kernel 0: preconvert fc1w (80x768 f32, [n*8+c][k]) into
// fragment-major hi/lo bf16: fw2[k/8][col=80][8], col = n*8+c.
__global__ __launch_bounds__(256) void k0_cvt(const float* __restrict__ w,
                                              short* __restrict__ hi,
                                              short* __restrict__ lo) {
    int i = blockIdx.x * 256 + threadIdx.x;   // output index
    if (i < NTq * CAPq * Dq) {
        int k8 = i / 640;
        int rem = i - k8 * 640;
        int o = rem >> 3, kf = rem & 7;
        float f = w[o * Dq + k8 * 8 + kf];
        hi[i] = bfhi(f);
        lo[i] = bflo(f);
    }
}

// ---------------- k1 compute helper: one 32-k chunk, 5 N-fragments
__device__ __forceinline__ void k1_comp(const float* xv, const short* pwh, const short* pwl,
                                        int ko80, f32x4* acc) {
    bf16x8 ah, al;
#pragma unroll
    for (int i = 0; i < 8; ++i) { ah[i] = bfhi(xv[i]); al[i] = bflo(xv[i]); }
#pragma unroll
    for (int f = 0; f < 5; ++f) {
        bf16x8 bh = *reinterpret_cast<const bf16x8*>(pwh + ko80 + f * 128);
        bf16x8 bl = *reinterpret_cast<const bf16x8*>(pwl + ko80 + f * 128);
        acc[f] = __builtin_amdgcn_mfma_f32_16x16x32_bf16(al, bh, acc[f], 0, 0, 0);
        acc[f] = __builtin_amdgcn_mfma_f32_16x16x32_bf16(ah, bl, acc[f], 0, 0, 0);
        acc[f] = __builtin_amdgcn_mfma_f32_16x16x32_bf16(ah, bh, acc[f], 0, 0, 0);
    }
}

// ---------------- Kernel 1 (split-bf16 MFMA): sem = x·fc1w^T + b, squash over routes,
// write u2 hi/lo bf16, layout [n][s][b][c].
// Block: 16 rows x 4 k-part waves (192 k each); LDS 4-way k-reduce. Grid 1024.
__global__ __launch_bounds__(256) void k1_sem(const float* __restrict__ x,
                                              const short* __restrict__ fwh,
                                              const short* __restrict__ fwl,
                                              const float* __restrict__ fc1b,
                                              short* __restrict__ u_hi,
                                              short* __restrict__ u_lo) {
    __shared__ float redS[3][20][64];
    const int t = threadIdx.x;
    const int L = t & 63, w = t >> 6;          // w = k-part 0..3
    const int colL = L & 15, kg = L >> 4;
    const int rowA = blockIdx.x * 16 + colL;   // A-fragment row

    f32x4 acc[5];
#pragma unroll
    for (int f = 0; f < 5; ++f) acc[f] = (f32x4){0.f, 0.f, 0.f, 0.f};

    const float* px = x + (size_t)rowA * Dq + w * 192 + kg * 8;
    const short* pwh = fwh + kg * 640 + colL * 8;
    const short* pwl = fwl + kg * 640 + colL * 8;

    float xv0[8], xv1[8];
    *reinterpret_cast<float4*>(&xv0[0]) = *reinterpret_cast<const float4*>(px);
    *reinterpret_cast<float4*>(&xv0[4]) = *reinterpret_cast<const float4*>(px + 4);

    for (int kc = 0; kc < 192; kc += 64) {
        {   // prefetch chunk kc+32
            const float* p = px + kc + 32;
            *reinterpret_cast<float4*>(&xv1[0]) = *reinterpret_cast<const float4*>(p);
            *reinterpret_cast<float4*>(&xv1[4]) = *reinterpret_cast<const float4*>(p + 4);
        }
        __builtin_amdgcn_sched_barrier(0);
        k1_comp(xv0, pwh, pwl, (w * 192 + kc) * 80, acc);
        __builtin_amdgcn_sched_barrier(0);
        {   // prefetch chunk kc+64 (dummy on last iter)
            int kn = (kc + 64 < 192) ? kc + 64 : 0;
            const float* p = px + kn;
            *reinterpret_cast<float4*>(&xv0[0]) = *reinterpret_cast<const float4*>(p);
            *reinterpret_cast<float4*>(&xv0[4]) = *reinterpret_cast<const float4*>(p + 4);
        }
        __builtin_amdgcn_sched_barrier(0);
        k1_comp(xv1, pwh, pwl, (w * 192 + kc + 32) * 80, acc);
        __builtin_amdgcn_sched_barrier(0);
    }

    if (w > 0) {
#pragma unroll
        for (int f = 0; f < 5; ++f)
#pragma unroll
            for (int g = 0; g < 4; ++g)
                redS[w - 1][f * 4 + g][L] = acc[f][g];
    }
    __syncthreads();
    if (w == 0) {
        float bias[5];
#pragma unroll
        for (int f = 0; f < 5; ++f) bias[f] = fc1b[f * 16 + colL];
        const int cc = colL & 7;
        const int npar = (colL >> 3) & 1;
#pragma unroll
        for (int reg = 0; reg < 4; ++reg) {
            const int row = blockIdx.x * 16 + kg * 4 + reg;    // C/D: row=(L>>4)*4+reg
            const int b = row >> 8, s = row & 255;
            float v[5], sqp = 0.f;
#pragma unroll
            for (int f = 0; f < 5; ++f) {
                v[f] = acc[f][reg] + redS[0][f * 4 + reg][L] + redS[1][f * 4 + reg][L]
                     + redS[2][f * 4 + reg][L] + bias[f];
                sqp = fmaf(v[f], v[f], sqp);
            }
            float sq = sqp + __shfl_xor(sqp, 8, 64);       // pair even/odd routes (colL ^ 8)
            float scale = (sq / (1.f + sq)) / sqrtf(sq);
#pragma unroll
            for (int f = 0; f < 5; ++f) {
                int n = 2 * f + npar;
                size_t off = (((size_t)n * 256 + s) * 64 + b) * 8 + cc;   // u2[n][s][b][c]
                float val = v[f] * scale;
                u_hi[off] = bfhi(val);
                u_lo[off] = bflo(val);
            }
        }
    }
}

// ---------------- k2 compute helper: one 32-k chunk, 4 M-fragments
__device__ __forceinline__ void k2_comp(const float* bv, const short* puh, const short* pul,
                                        int ao, f32x4* acc) {
    bf16x8 bh, bl;
#pragma unroll
    for (int i = 0; i < 8; ++i) { bh[i] = bfhi(bv[i]); bl[i] = bflo(bv[i]); }
#pragma unroll
    for (int m = 0; m < 4; ++m) {
        bf16x8 ah = *reinterpret_cast<const bf16x8*>(puh + ao + m * 128);
        bf16x8 al = *reinterpret_cast<const bf16x8*>(pul + ao + m * 128);
        acc[m] = __builtin_amdgcn_mfma_f32_16x16x32_bf16(al, bh, acc[m], 0, 0, 0);
        acc[m] = __builtin_amdgcn_mfma_f32_16x16x32_bf16(ah, bl, acc[m], 0, 0, 0);
        acc[m] = __builtin_amdgcn_mfma_f32_16x16x32_bf16(ah, bh, acc[m], 0, 0, 0);
    }
}

// ---------------- Kernel 2 (split-bf16 MFMA, pinned prefetch, 4-way LDS k-reduce):
// part[ks][c][b][r][l] = sum_{k in half ks} u[b,r,k]*rw[c,r,k,l]
// Block = 512 thr = 8 waves: lh = w&1 (16 l), kh = w>>1 (256-k quarter).
// grid.x: lq = x&7 (32-l chunk), ks = x>>3 (1024-k half); y=r (skip r>task), z=c.
__global__ __launch_bounds__(512) void k2_priors(const short* __restrict__ u_hi,
                                                 const short* __restrict__ u_lo,
                                                 const float* __restrict__ rw,
                                                 const int* __restrict__ task_p,
                                                 float* __restrict__ part) {
    const int r = blockIdx.y;
    if (r > *task_p) return;
    __shared__ float redS[3][2][16][64];
    const int t = threadIdx.x;
    const int L = t & 63, w = t >> 6;
    const int colL = L & 15, kg = L >> 4;
    const int lq = blockIdx.x & 7, ks = blockIdx.x >> 3;
    const int c = blockIdx.z;
    const int lh = w & 1, kh = w >> 1;           // kh 0..3
    const int l = lq * 32 + lh * 16 + colL;
    const int kw0 = ks * 1024 + kh * 256;
    const int s00 = kw0 >> 3;

    f32x4 acc[4];
#pragma unroll
    for (int m = 0; m < 4; ++m) acc[m] = (f32x4){0.f, 0.f, 0.f, 0.f};

    const float* pb = rw + ((size_t)(c * NTq + r) * SCq + kw0 + kg * 8) * Sq + l;
    const short* puh = u_hi + (((size_t)r * 256 + s00 + kg) * 64 + colL) * 8;
    const short* pul = u_lo + (((size_t)r * 256 + s00 + kg) * 64 + colL) * 8;

    float bv0[8], bv1[8];
#pragma unroll
    for (int i = 0; i < 8; ++i) bv0[i] = pb[(size_t)i * Sq];

    for (int kc = 0; kc < 256; kc += 64) {
        {   // prefetch B chunk kc+32
            const float* p = pb + (size_t)(kc + 32) * Sq;
#pragma unroll
            for (int i = 0; i < 8; ++i) bv1[i] = p[(size_t)i * Sq];
        }
        __builtin_amdgcn_sched_barrier(0);
        k2_comp(bv0, puh, pul, kc * 64, acc);
        __builtin_amdgcn_sched_barrier(0);
        {   // prefetch B chunk kc+64 (dummy on last iter)
            int kn = (kc + 64 < 256) ? kc + 64 : 0;
            const float* p = pb + (size_t)kn * Sq;
#pragma unroll
            for (int i = 0; i < 8; ++i) bv0[i] = p[(size_t)i * Sq];
        }
        __builtin_amdgcn_sched_barrier(0);
        k2_comp(bv1, puh, pul, (kc + 32) * 64, acc);
        __builtin_amdgcn_sched_barrier(0);
    }

    // 4-way cross-kh reduction in LDS; kh==0 waves write out
    if (kh > 0) {
#pragma unroll
        for (int m = 0; m < 4; ++m)
#pragma unroll
            for (int g = 0; g < 4; ++g)
                redS[kh - 1][lh][m * 4 + g][L] = acc[m][g];
    }
    __syncthreads();
    if (kh == 0) {
#pragma unroll
        for (int m = 0; m < 4; ++m) {
#pragma unroll
            for (int g = 0; g < 4; ++g) {
                float v = acc[m][g] + redS[0][lh][m * 4 + g][L]
                        + redS[1][lh][m * 4 + g][L] + redS[2][lh][m * 4 + g][L];
                int b = m * 16 + kg * 4 + g;
                part[(size_t)ks * 1310720 + ((size_t)(c * Bq + b) * NTq + r) * Sq + l] = v;
            }
        }
    }
}

// ---------------- Kernel 3: dynamic routing, one WAVE per (c,b); priors in registers.
// Key identity: <priors, out> = scale * <priors, vote>, so all 10 dots + ||vote||^2
// reduce in ONE batched 6-hop shfl_xor butterfly (no LDS, no barriers).
__global__ __launch_bounds__(256) void k3_route(const float* __restrict__ part,
                                                const int* __restrict__ task_p,
                                                float* __restrict__ vote_out) {
    const int t = threadIdx.x;
    const int lane = t & 63, w = t >> 6;
    const int wid = blockIdx.x * 4 + w;          // 0..511
    const int b = wid & 63, c = wid >> 6;
    const int task = *task_p;

    float pr[NTq][4];
    const float* p0 = part + ((size_t)(c * Bq + b) * NTq) * Sq + lane * 4;
#pragma unroll
    for (int r = 0; r < NTq; ++r) {
        f32x4 a = *reinterpret_cast<const f32x4*>(p0 + r * Sq);
        f32x4 d = *reinterpret_cast<const f32x4*>(p0 + 1310720 + r * Sq);
#pragma unroll
        for (int ii = 0; ii < 4; ++ii) pr[r][ii] = a[ii] + d[ii];
    }

    float logits[NTq];
#pragma unroll
    for (int r = 0; r < NTq; ++r) logits[r] = 0.f;
    float vote[4];

    for (int it = 0; it < 3; ++it) {
        float m = -1e30f;
#pragma unroll
        for (int r = 0; r < NTq; ++r) if (r <= task) m = fmaxf(m, logits[r]);
        float p[NTq]; float s = 0.f;
#pragma unroll
        for (int r = 0; r < NTq; ++r) {
            p[r] = (r <= task) ? expf(logits[r] - m) : 0.f;
            s += p[r];
        }
        float inv = 1.f / s;
#pragma unroll
        for (int ii = 0; ii < 4; ++ii) vote[ii] = 0.f;
#pragma unroll
        for (int r = 0; r < NTq; ++r) {
            float pw = p[r] * inv;
#pragma unroll
            for (int ii = 0; ii < 4; ++ii) vote[ii] = fmaf(pw, pr[r][ii], vote[ii]);
        }
        if (it == 2) break;

        float vals[11];
#pragma unroll
        for (int r = 0; r < NTq; ++r) {
            float d = 0.f;
#pragma unroll
            for (int ii = 0; ii < 4; ++ii) d = fmaf(pr[r][ii], vote[ii], d);
            vals[r] = d;
        }
        {
            float d = 0.f;
#pragma unroll
            for (int ii = 0; ii < 4; ++ii) d = fmaf(vote[ii], vote[ii], d);
            vals[10] = d;
        }
#pragma unroll
        for (int o = 32; o > 0; o >>= 1) {
#pragma unroll
            for (int v = 0; v < 11; ++v) vals[v] += __shfl_xor(vals[v], o, 64);
        }
        float sq = vals[10];
        float scale = (sq / (1.f + sq)) / sqrtf(sq);
#pragma unroll
        for (int r = 0; r < NTq; ++r)
            if (r <= task) logits[r] += scale * vals[r];
    }

    f32x4 vo;
#pragma unroll
    for (int ii = 0; ii < 4; ++ii) vo[ii] = vote[ii];
    *reinterpret_cast<f32x4*>(vote_out + (size_t)(c * Bq + b) * Sq + lane * 4) = vo;
}

// ---------------- Kernel 4: h gather (flat reinterpret) + Linear(CAP->768)
__global__ __launch_bounds__(256) void k4_out(const float* __restrict__ vote, // [CAP][B][S] flat
                                              const float* __restrict__ lw,   // [768][8]
                                              const float* __restrict__ lb,   // [768]
                                              float* __restrict__ out) {      // [B,S,768]
    __shared__ float hS[8][8];
    const int t = threadIdx.x;
    if (t < 64) {
        int rr = t >> 3, cc = t & 7;
        size_t row = (size_t)blockIdx.x * 8 + rr;   // b'*256 + s'
        size_t flat = row * 8 + cc;                 // b'*2048 + s'*8 + c'
        int c = (int)(flat >> 14);                  // /16384
        int rem = (int)(flat & 16383);
        int bb = rem >> 8;
        int l = rem & 255;
        hS[rr][cc] = vote[(size_t)c*16384 + bb*256 + l];
    }
    float lwr[3][8];
    float lbr[3];
#pragma unroll
    for (int dd = 0; dd < 3; ++dd) {
        int d = t + dd*256;
        float4 a = *reinterpret_cast<const float4*>(&lw[(size_t)d*8]);
        float4 b2 = *reinterpret_cast<const float4*>(&lw[(size_t)d*8 + 4]);
        lwr[dd][0]=a.x; lwr[dd][1]=a.y; lwr[dd][2]=a.z; lwr[dd][3]=a.w;
        lwr[dd][4]=b2.x; lwr[dd][5]=b2.y; lwr[dd][6]=b2.z; lwr[dd][7]=b2.w;
        lbr[dd] = lb[d];
    }
    __syncthreads();
#pragma unroll
    for (int rr = 0; rr < 8; ++rr) {
        size_t row = (size_t)blockIdx.x * 8 + rr;
#pragma unroll
        for (int dd = 0; dd < 3; ++dd) {
            float acc = lbr[dd];
#pragma unroll
            for (int c = 0; c < 8; ++c) acc = fmaf(hS[rr][c], lwr[dd][c], acc);
            out[row*Dq + t + dd*256] = acc;
        }
    }
}

extern "C" void kernel_launch(void* const* d_in, const int* in_sizes, int n_in,
                              void* d_out, int out_size, void* d_ws, size_t ws_size,
                              hipStream_t stream) {
    const float* x    = (const float*)d_in[0];
    const int*   task = (const int*)d_in[1];
    const float* fc1w = (const float*)d_in[2];
    const float* fc1b = (const float*)d_in[3];
    const float* rw   = (const float*)d_in[4];
    const float* lw   = (const float*)d_in[5];
    const float* lb   = (const float*)d_in[6];
    float* out = (float*)d_out;

    short* u_hi = (short*)d_ws;                              // 2,621,440 B
    short* u_lo = u_hi + 1310720;                            // 2,621,440 B
    float* part = (float*)((char*)d_ws + 5242880);           // 10,485,760 B
    float* vote = part + 2621440;                            // 524,288 B
    short* fwh  = (short*)((char*)d_ws + 16252928);          // 122,880 B
    short* fwl  = fwh + 61440;                               // 122,880 B

    k0_cvt<<<240, 256, 0, stream>>>(fc1w, fwh, fwl);
    k1_sem<<<1024, 256, 0, stream>>>(x, fwh, fwl, fc1b, u_hi, u_lo);
    dim3 g2(16, NTq, CAPq);
    k2_priors<<<g2, 512, 0, stream>>>(u_hi, u_lo, rw, task, part);
    k3_route<<<128, 256, 0, stream>>>(part, task, vote);
    k4_out<<<2048, 256, 0, stream>>>(vote, lw, lb, out);
}

// Round 11
// 77.857 us; speedup vs baseline: 3.1462x; 1.0026x over previous
//
#include <hip/hip_runtime.h>
#include <hip/hip_bf16.h>

#define Bq 64
#define Sq 256
#define Dq 768
#define CAPq 8
#define NTq 10
#define SCq 2048   // S*CAP

typedef short bf16x8 __attribute__((ext_vector_type(8)));
typedef float f32x4  __attribute__((ext_vector_type(4)));

// split f32 into hi/lo bf16 (bit-truncation; f ~= hi + lo, residual ~2^-17 |f|)
static __device__ __forceinline__ short bfhi(float f) {
    return (short)(__float_as_uint(f) >> 16);
}
static __device__ __forceinline__ short bflo(float f) {
    float hi = __uint_as_float(__float_as_uint(f) & 0xFFFF0000u);
    return (short)(__float_as_uint(f - hi) >> 16);
}

// ---------------- Kernel 0: preconvert fc1w (80x768 f32, [n*8+c][k]) into
// fragment-major hi/lo bf16: fw2[k/8][col=80][8], col = n*8+c.
__global__ __launch_bounds__(256) void k0_cvt(const float* __restrict__ w,
                                              short* __restrict__ hi,
                                              short* __restrict__ lo) {
    int i = blockIdx.x * 256 + threadIdx.x;   // output index
    if (i < NTq * CAPq * Dq) {
        int k8 = i / 640;
        int rem = i - k8 * 640;
        int o = rem >> 3, kf = rem & 7;
        float f = w[o * Dq + k8 * 8 + kf];
        hi[i] = bfhi(f);
        lo[i] = bflo(f);
    }
}

// ---------------- k1 compute helper: one 32-k chunk, 5 N-fragments
__device__ __forceinline__ void k1_comp(const float* xv, const short* pwh, const short* pwl,
                                        int ko80, f32x4* acc) {
    bf16x8 ah, al;
#pragma unroll
    for (int i = 0; i < 8; ++i) { ah[i] = bfhi(xv[i]); al[i] = bflo(xv[i]); }
#pragma unroll
    for (int f = 0; f < 5; ++f) {
        bf16x8 bh = *reinterpret_cast<const bf16x8*>(pwh + ko80 + f * 128);
        bf16x8 bl = *reinterpret_cast<const bf16x8*>(pwl + ko80 + f * 128);
        acc[f] = __builtin_amdgcn_mfma_f32_16x16x32_bf16(al, bh, acc[f], 0, 0, 0);
        acc[f] = __builtin_amdgcn_mfma_f32_16x16x32_bf16(ah, bl, acc[f], 0, 0, 0);
        acc[f] = __builtin_amdgcn_mfma_f32_16x16x32_bf16(ah, bh, acc[f], 0, 0, 0);
    }
}

// ---------------- Kernel 1 (split-bf16 MFMA): sem = x·fc1w^T + b, squash over routes,
// write u2 hi/lo bf16, layout [n][s][b][c].
// Block: 16 rows x 4 k-part waves (192 k each); LDS 4-way k-reduce. Grid 1024.
__global__ __launch_bounds__(256) void k1_sem(const float* __restrict__ x,
                                              const short* __restrict__ fwh,
                                              const short* __restrict__ fwl,
                                              const float* __restrict__ fc1b,
                                              short* __restrict__ u_hi,
                                              short* __restrict__ u_lo) {
    __shared__ float redS[3][20][64];
    const int t = threadIdx.x;
    const int L = t & 63, w = t >> 6;          // w = k-part 0..3
    const int colL = L & 15, kg = L >> 4;
    const int rowA = blockIdx.x * 16 + colL;   // A-fragment row

    f32x4 acc[5];
#pragma unroll
    for (int f = 0; f < 5; ++f) acc[f] = (f32x4){0.f, 0.f, 0.f, 0.f};

    const float* px = x + (size_t)rowA * Dq + w * 192 + kg * 8;
    const short* pwh = fwh + kg * 640 + colL * 8;
    const short* pwl = fwl + kg * 640 + colL * 8;

    float xv0[8], xv1[8];
    *reinterpret_cast<float4*>(&xv0[0]) = *reinterpret_cast<const float4*>(px);
    *reinterpret_cast<float4*>(&xv0[4]) = *reinterpret_cast<const float4*>(px + 4);

    for (int kc = 0; kc < 192; kc += 64) {
        {   // prefetch chunk kc+32
            const float* p = px + kc + 32;
            *reinterpret_cast<float4*>(&xv1[0]) = *reinterpret_cast<const float4*>(p);
            *reinterpret_cast<float4*>(&xv1[4]) = *reinterpret_cast<const float4*>(p + 4);
        }
        __builtin_amdgcn_sched_barrier(0);
        k1_comp(xv0, pwh, pwl, (w * 192 + kc) * 80, acc);
        __builtin_amdgcn_sched_barrier(0);
        {   // prefetch chunk kc+64 (dummy on last iter)
            int kn = (kc + 64 < 192) ? kc + 64 : 0;
            const float* p = px + kn;
            *reinterpret_cast<float4*>(&xv0[0]) = *reinterpret_cast<const float4*>(p);
            *reinterpret_cast<float4*>(&xv0[4]) = *reinterpret_cast<const float4*>(p + 4);
        }
        __builtin_amdgcn_sched_barrier(0);
        k1_comp(xv1, pwh, pwl, (w * 192 + kc + 32) * 80, acc);
        __builtin_amdgcn_sched_barrier(0);
    }

    if (w > 0) {
#pragma unroll
        for (int f = 0; f < 5; ++f)
#pragma unroll
            for (int g = 0; g < 4; ++g)
                redS[w - 1][f * 4 + g][L] = acc[f][g];
    }
    __syncthreads();
    if (w == 0) {
        float bias[5];
#pragma unroll
        for (int f = 0; f < 5; ++f) bias[f] = fc1b[f * 16 + colL];
        const int cc = colL & 7;
        const int npar = (colL >> 3) & 1;
#pragma unroll
        for (int reg = 0; reg < 4; ++reg) {
            const int row = blockIdx.x * 16 + kg * 4 + reg;    // C/D: row=(L>>4)*4+reg
            const int b = row >> 8, s = row & 255;
            float v[5], sqp = 0.f;
#pragma unroll
            for (int f = 0; f < 5; ++f) {
                v[f] = acc[f][reg] + redS[0][f * 4 + reg][L] + redS[1][f * 4 + reg][L]
                     + redS[2][f * 4 + reg][L] + bias[f];
                sqp = fmaf(v[f], v[f], sqp);
            }
            float sq = sqp + __shfl_xor(sqp, 8, 64);       // pair even/odd routes (colL ^ 8)
            float scale = (sq / (1.f + sq)) / sqrtf(sq);
#pragma unroll
            for (int f = 0; f < 5; ++f) {
                int n = 2 * f + npar;
                size_t off = (((size_t)n * 256 + s) * 64 + b) * 8 + cc;   // u2[n][s][b][c]
                float val = v[f] * scale;
                u_hi[off] = bfhi(val);
                u_lo[off] = bflo(val);
            }
        }
    }
}

// ---------------- k2 compute helper: one 32-k chunk, 4 M-frags x 2 N-frags (even/odd l)
__device__ __forceinline__ void k2_comp2(const float2* bv, const short* puh, const short* pul,
                                         int ao, f32x4* accE, f32x4* accO) {
    bf16x8 bhE, blE, bhO, blO;
#pragma unroll
    for (int i = 0; i < 8; ++i) {
        bhE[i] = bfhi(bv[i].x); blE[i] = bflo(bv[i].x);
        bhO[i] = bfhi(bv[i].y); blO[i] = bflo(bv[i].y);
    }
#pragma unroll
    for (int m = 0; m < 4; ++m) {
        bf16x8 ah = *reinterpret_cast<const bf16x8*>(puh + ao + m * 128);
        bf16x8 al = *reinterpret_cast<const bf16x8*>(pul + ao + m * 128);
        accE[m] = __builtin_amdgcn_mfma_f32_16x16x32_bf16(al, bhE, accE[m], 0, 0, 0);
        accE[m] = __builtin_amdgcn_mfma_f32_16x16x32_bf16(ah, blE, accE[m], 0, 0, 0);
        accE[m] = __builtin_amdgcn_mfma_f32_16x16x32_bf16(ah, bhE, accE[m], 0, 0, 0);
        accO[m] = __builtin_amdgcn_mfma_f32_16x16x32_bf16(al, bhO, accO[m], 0, 0, 0);
        accO[m] = __builtin_amdgcn_mfma_f32_16x16x32_bf16(ah, blO, accO[m], 0, 0, 0);
        accO[m] = __builtin_amdgcn_mfma_f32_16x16x32_bf16(ah, bhO, accO[m], 0, 0, 0);
    }
}

// ---------------- Kernel 2 (split-bf16 MFMA, paired N-frags, pinned prefetch, 4-way LDS k-reduce):
// part[ks][c][b][r][l] = sum_{k in half ks} u[b,r,k]*rw[c,r,k,l]
// Block = 256 thr = 4 kh waves; each wave covers 32 l (even/odd frag pair) x 64 b x 256 k.
// grid.x: lq = x&7 (32-l chunk), ks = x>>3 (1024-k half); y=r (skip r>task), z=c.
__global__ __launch_bounds__(256, 3) void k2_priors(const short* __restrict__ u_hi,
                                                    const short* __restrict__ u_lo,
                                                    const float* __restrict__ rw,
                                                    const int* __restrict__ task_p,
                                                    float* __restrict__ part) {
    const int r = blockIdx.y;
    if (r > *task_p) return;
    __shared__ float redS[3][2][16][64];
    const int t = threadIdx.x;
    const int L = t & 63, kh = t >> 6;           // kh 0..3
    const int colL = L & 15, kg = L >> 4;
    const int lq = blockIdx.x & 7, ks = blockIdx.x >> 3;
    const int c = blockIdx.z;
    const int le = lq * 32 + 2 * colL;           // even l for this lane (odd = +1)
    const int kw0 = ks * 1024 + kh * 256;
    const int s00 = kw0 >> 3;

    f32x4 accE[4], accO[4];
#pragma unroll
    for (int m = 0; m < 4; ++m) {
        accE[m] = (f32x4){0.f, 0.f, 0.f, 0.f};
        accO[m] = (f32x4){0.f, 0.f, 0.f, 0.f};
    }

    const float* pb = rw + ((size_t)(c * NTq + r) * SCq + kw0 + kg * 8) * Sq + le;
    const short* puh = u_hi + (((size_t)r * 256 + s00 + kg) * 64 + colL) * 8;
    const short* pul = u_lo + (((size_t)r * 256 + s00 + kg) * 64 + colL) * 8;

    float2 bv0[8], bv1[8];
#pragma unroll
    for (int i = 0; i < 8; ++i) bv0[i] = *reinterpret_cast<const float2*>(pb + (size_t)i * Sq);

    for (int kc = 0; kc < 256; kc += 64) {
        {   // prefetch B chunk kc+32
            const float* p = pb + (size_t)(kc + 32) * Sq;
#pragma unroll
            for (int i = 0; i < 8; ++i) bv1[i] = *reinterpret_cast<const float2*>(p + (size_t)i * Sq);
        }
        __builtin_amdgcn_sched_barrier(0);
        k2_comp2(bv0, puh, pul, kc * 64, accE, accO);
        __builtin_amdgcn_sched_barrier(0);
        {   // prefetch B chunk kc+64 (dummy on last iter)
            int kn = (kc + 64 < 256) ? kc + 64 : 0;
            const float* p = pb + (size_t)kn * Sq;
#pragma unroll
            for (int i = 0; i < 8; ++i) bv0[i] = *reinterpret_cast<const float2*>(p + (size_t)i * Sq);
        }
        __builtin_amdgcn_sched_barrier(0);
        k2_comp2(bv1, puh, pul, (kc + 32) * 64, accE, accO);
        __builtin_amdgcn_sched_barrier(0);
    }

    // 4-way cross-kh reduction in LDS; kh==0 waves write out
    if (kh > 0) {
#pragma unroll
        for (int m = 0; m < 4; ++m)
#pragma unroll
            for (int g = 0; g < 4; ++g) {
                redS[kh - 1][0][m * 4 + g][L] = accE[m][g];
                redS[kh - 1][1][m * 4 + g][L] = accO[m][g];
            }
    }
    __syncthreads();
    if (kh == 0) {
#pragma unroll
        for (int m = 0; m < 4; ++m) {
#pragma unroll
            for (int g = 0; g < 4; ++g) {
                float vE = accE[m][g] + redS[0][0][m * 4 + g][L]
                         + redS[1][0][m * 4 + g][L] + redS[2][0][m * 4 + g][L];
                float vO = accO[m][g] + redS[0][1][m * 4 + g][L]
                         + redS[1][1][m * 4 + g][L] + redS[2][1][m * 4 + g][L];
                int bb = m * 16 + kg * 4 + g;
                size_t idx = (size_t)ks * 1310720 + ((size_t)(c * Bq + bb) * NTq + r) * Sq + le;
                float2 vv; vv.x = vE; vv.y = vO;
                *reinterpret_cast<float2*>(part + idx) = vv;
            }
        }
    }
}

// ---------------- Kernel 3+4 fused: routing per (c,b) + direct output projection.
// Block = 4 waves, grid 512 (one block per (c,b)). Each wave REDUNDANTLY computes the
// routing (priors in registers, batched 6-hop shfl_xor butterfly), then writes its own
// 8 output rows: out rows for (c,b) are c*2048+b*32+q, q=0..31, row q using vote[q*8..q*8+7].
__global__ __launch_bounds__(256) void k34_route_out(const float* __restrict__ part,
                                                     const int* __restrict__ task_p,
                                                     const float* __restrict__ lw,   // [768][8]
                                                     const float* __restrict__ lb,   // [768]
                                                     float* __restrict__ out) {      // [B,S,768]
    const int t = threadIdx.x;
    const int lane = t & 63, w = t >> 6;
    const int b = blockIdx.x & 63, c = blockIdx.x >> 6;
    const int task = *task_p;

    float pr[NTq][4];
    const float* p0 = part + ((size_t)(c * Bq + b) * NTq) * Sq + lane * 4;
#pragma unroll
    for (int r = 0; r < NTq; ++r) {
        f32x4 a = *reinterpret_cast<const f32x4*>(p0 + r * Sq);
        f32x4 d = *reinterpret_cast<const f32x4*>(p0 + 1310720 + r * Sq);
#pragma unroll
        for (int ii = 0; ii < 4; ++ii) pr[r][ii] = a[ii] + d[ii];
    }

    float logits[NTq];
#pragma unroll
    for (int r = 0; r < NTq; ++r) logits[r] = 0.f;
    float vote[4];

    for (int it = 0; it < 3; ++it) {
        float m = -1e30f;
#pragma unroll
        for (int r = 0; r < NTq; ++r) if (r <= task) m = fmaxf(m, logits[r]);
        float p[NTq]; float s = 0.f;
#pragma unroll
        for (int r = 0; r < NTq; ++r) {
            p[r] = (r <= task) ? expf(logits[r] - m) : 0.f;
            s += p[r];
        }
        float inv = 1.f / s;
#pragma unroll
        for (int ii = 0; ii < 4; ++ii) vote[ii] = 0.f;
#pragma unroll
        for (int r = 0; r < NTq; ++r) {
            float pw = p[r] * inv;
#pragma unroll
            for (int ii = 0; ii < 4; ++ii) vote[ii] = fmaf(pw, pr[r][ii], vote[ii]);
        }
        if (it == 2) break;

        float vals[11];
#pragma unroll
        for (int r = 0; r < NTq; ++r) {
            float d = 0.f;
#pragma unroll
            for (int ii = 0; ii < 4; ++ii) d = fmaf(pr[r][ii], vote[ii], d);
            vals[r] = d;
        }
        {
            float d = 0.f;
#pragma unroll
            for (int ii = 0; ii < 4; ++ii) d = fmaf(vote[ii], vote[ii], d);
            vals[10] = d;
        }
#pragma unroll
        for (int o = 32; o > 0; o >>= 1) {
#pragma unroll
            for (int v = 0; v < 11; ++v) vals[v] += __shfl_xor(vals[v], o, 64);
        }
        float sq = vals[10];
        float scale = (sq / (1.f + sq)) / sqrtf(sq);
#pragma unroll
        for (int r = 0; r < NTq; ++r)
            if (r <= task) logits[r] += scale * vals[r];
    }

    // ---- epilogue: wave w writes out rows rbase..rbase+7 (q = w*8+j), row j uses
    // vote[l], l = (w*8+j)*8 + jj, held in lanes 16w+2j (+1), regs jj&3.
    float v[8][8];
#pragma unroll
    for (int j = 0; j < 8; ++j) {
        int s0 = w * 16 + 2 * j;
#pragma unroll
        for (int ii = 0; ii < 4; ++ii) v[j][ii]     = __shfl(vote[ii], s0, 64);
#pragma unroll
        for (int ii = 0; ii < 4; ++ii) v[j][4 + ii] = __shfl(vote[ii], s0 + 1, 64);
    }
    const int rbase = c * 2048 + b * 32 + w * 8;
#pragma unroll
    for (int dd = 0; dd < 12; ++dd) {
        int d = lane + dd * 64;
        float4 wa = *reinterpret_cast<const float4*>(lw + (size_t)d * 8);
        float4 wb = *reinterpret_cast<const float4*>(lw + (size_t)d * 8 + 4);
        float lbv = lb[d];
#pragma unroll
        for (int j = 0; j < 8; ++j) {
            float acc = lbv;
            acc = fmaf(v[j][0], wa.x, acc);
            acc = fmaf(v[j][1], wa.y, acc);
            acc = fmaf(v[j][2], wa.z, acc);
            acc = fmaf(v[j][3], wa.w, acc);
            acc = fmaf(v[j][4], wb.x, acc);
            acc = fmaf(v[j][5], wb.y, acc);
            acc = fmaf(v[j][6], wb.z, acc);
            acc = fmaf(v[j][7], wb.w, acc);
            out[(size_t)(rbase + j) * Dq + d] = acc;
        }
    }
}

extern "C" void kernel_launch(void* const* d_in, const int* in_sizes, int n_in,
                              void* d_out, int out_size, void* d_ws, size_t ws_size,
                              hipStream_t stream) {
    const float* x    = (const float*)d_in[0];
    const int*   task = (const int*)d_in[1];
    const float* fc1w = (const float*)d_in[2];
    const float* fc1b = (const float*)d_in[3];
    const float* rw   = (const float*)d_in[4];
    const float* lw   = (const float*)d_in[5];
    const float* lb   = (const float*)d_in[6];
    float* out = (float*)d_out;

    short* u_hi = (short*)d_ws;                              // 2,621,440 B
    short* u_lo = u_hi + 1310720;                            // 2,621,440 B
    float* part = (float*)((char*)d_ws + 5242880);           // 10,485,760 B
    short* fwh  = (short*)((char*)d_ws + 16252928);          // 122,880 B
    short* fwl  = fwh + 61440;                               // 122,880 B

    k0_cvt<<<240, 256, 0, stream>>>(fc1w, fwh, fwl);
    k1_sem<<<1024, 256, 0, stream>>>(x, fwh, fwl, fc1b, u_hi, u_lo);
    dim3 g2(16, NTq, CAPq);
    k2_priors<<<g2, 256, 0, stream>>>(u_hi, u_lo, rw, task, part);
    k34_route_out<<<512, 256, 0, stream>>>(part, task, lw, lb, out);
}

// Round 12
// 76.235 us; speedup vs baseline: 3.2132x; 1.0213x over previous
//
#include <hip/hip_runtime.h>
#include <hip/hip_bf16.h>

#define Bq 64
#define Sq 256
#define Dq 768
#define CAPq 8
#define NTq 10
#define SCq 2048   // S*CAP

typedef short bf16x8 __attribute__((ext_vector_type(8)));
typedef float f32x4  __attribute__((ext_vector_type(4)));

// split f32 into hi/lo bf16 (bit-truncation; f ~= hi + lo, residual ~2^-17 |f|)
static __device__ __forceinline__ short bfhi(float f) {
    return (short)(__float_as_uint(f) >> 16);
}
static __device__ __forceinline__ short bflo(float f) {
    float hi = __uint_as_float(__float_as_uint(f) & 0xFFFF0000u);
    return (short)(__float_as_uint(f - hi) >> 16);
}

// ---------------- Kernel 0: preconvert fc1w (80x768 f32, [n*8+c][k]) into
// fragment-major hi/lo bf16: fw2[k/8][col=80][8], col = n*8+c.
__global__ __launch_bounds__(256) void k0_cvt(const float* __restrict__ w,
                                              short* __restrict__ hi,
                                              short* __restrict__ lo) {
    int i = blockIdx.x * 256 + threadIdx.x;   // output index
    if (i < NTq * CAPq * Dq) {
        int k8 = i / 640;
        int rem = i - k8 * 640;
        int o = rem >> 3, kf = rem & 7;
        float f = w[o * Dq + k8 * 8 + kf];
        hi[i] = bfhi(f);
        lo[i] = bflo(f);
    }
}

// ---------------- Kernel 1 (split-bf16 MFMA, LDS-staged x): sem = x·fc1w^T + b,
// squash over routes, write u2 hi/lo bf16, layout [n][s][b][c].
// Block: 16 rows x 4 k-part waves (192 k each); x staged coalesced into LDS as
// fragment-major hi/lo bf16; 4-way LDS k-reduce (redS overlaid on xsh). Grid 1024.
__global__ __launch_bounds__(256) void k1_sem(const float* __restrict__ x,
                                              const short* __restrict__ fwh,
                                              const short* __restrict__ fwl,
                                              const float* __restrict__ fc1b,
                                              short* __restrict__ u_hi,
                                              short* __restrict__ u_lo) {
    __shared__ short xsh[12288];   // [k8=96][row=16][8] hi   (24 KB)
    __shared__ short xsl[12288];   // lo                      (24 KB)
    const int t = threadIdx.x;
    const int L = t & 63, w = t >> 6;          // w = k-part 0..3
    const int colL = L & 15, kg = L >> 4;
    const int R0 = blockIdx.x * 16;

    // ---- stage x[R0..R0+15][0..767] -> LDS hi/lo, coalesced (>=1KB contiguous spans)
    const float* xbase = x + (size_t)R0 * Dq;
#pragma unroll
    for (int i = 0; i < 12; ++i) {
        int li = t + i * 256;                  // float4 index, 0..3071
        int r = li / 192, j = li - r * 192;    // row, float4-within-row
        float4 v = *reinterpret_cast<const float4*>(xbase + (size_t)r * Dq + j * 4);
        int k8 = j >> 1, kf = (j & 1) * 4;
        int off = (k8 * 16 + r) * 8 + kf;
        short4 h4, l4;
        h4.x = bfhi(v.x); h4.y = bfhi(v.y); h4.z = bfhi(v.z); h4.w = bfhi(v.w);
        l4.x = bflo(v.x); l4.y = bflo(v.y); l4.z = bflo(v.z); l4.w = bflo(v.w);
        *reinterpret_cast<short4*>(&xsh[off]) = h4;
        *reinterpret_cast<short4*>(&xsl[off]) = l4;
    }
    __syncthreads();

    f32x4 acc[5];
#pragma unroll
    for (int f = 0; f < 5; ++f) acc[f] = (f32x4){0.f, 0.f, 0.f, 0.f};

    const short* pwh = fwh + kg * 640 + colL * 8;
    const short* pwl = fwl + kg * 640 + colL * 8;

#pragma unroll 2
    for (int kc = 0; kc < 192; kc += 32) {
        const int k8 = ((w * 192 + kc) >> 3) + kg;
        bf16x8 ah = *reinterpret_cast<const bf16x8*>(&xsh[(k8 * 16 + colL) * 8]);
        bf16x8 al = *reinterpret_cast<const bf16x8*>(&xsl[(k8 * 16 + colL) * 8]);
        const int ko80 = (w * 192 + kc) * 80;
#pragma unroll
        for (int f = 0; f < 5; ++f) {
            bf16x8 bh = *reinterpret_cast<const bf16x8*>(pwh + ko80 + f * 128);
            bf16x8 bl = *reinterpret_cast<const bf16x8*>(pwl + ko80 + f * 128);
            acc[f] = __builtin_amdgcn_mfma_f32_16x16x32_bf16(al, bh, acc[f], 0, 0, 0);
            acc[f] = __builtin_amdgcn_mfma_f32_16x16x32_bf16(ah, bl, acc[f], 0, 0, 0);
            acc[f] = __builtin_amdgcn_mfma_f32_16x16x32_bf16(ah, bh, acc[f], 0, 0, 0);
        }
    }

    // ---- 4-way k-reduce: redS overlaid on xsh (all waves done reading xs)
    float* redS = reinterpret_cast<float*>(xsh);   // [3][20][64] floats = 15360 B < 24 KB
    __syncthreads();
    if (w > 0) {
#pragma unroll
        for (int f = 0; f < 5; ++f)
#pragma unroll
            for (int g = 0; g < 4; ++g)
                redS[((w - 1) * 20 + f * 4 + g) * 64 + L] = acc[f][g];
    }
    __syncthreads();
    if (w == 0) {
        float bias[5];
#pragma unroll
        for (int f = 0; f < 5; ++f) bias[f] = fc1b[f * 16 + colL];
        const int cc = colL & 7;
        const int npar = (colL >> 3) & 1;
#pragma unroll
        for (int reg = 0; reg < 4; ++reg) {
            const int row = R0 + kg * 4 + reg;             // C/D: row=(L>>4)*4+reg
            const int b = row >> 8, s = row & 255;
            float v[5], sqp = 0.f;
#pragma unroll
            for (int f = 0; f < 5; ++f) {
                v[f] = acc[f][reg] + redS[(0 * 20 + f * 4 + reg) * 64 + L]
                     + redS[(1 * 20 + f * 4 + reg) * 64 + L]
                     + redS[(2 * 20 + f * 4 + reg) * 64 + L] + bias[f];
                sqp = fmaf(v[f], v[f], sqp);
            }
            float sq = sqp + __shfl_xor(sqp, 8, 64);       // pair even/odd routes (colL ^ 8)
            float scale = (sq / (1.f + sq)) / sqrtf(sq);
#pragma unroll
            for (int f = 0; f < 5; ++f) {
                int n = 2 * f + npar;
                size_t off = (((size_t)n * 256 + s) * 64 + b) * 8 + cc;   // u2[n][s][b][c]
                float val = v[f] * scale;
                u_hi[off] = bfhi(val);
                u_lo[off] = bflo(val);
            }
        }
    }
}

// ---------------- k2 compute helper: one 32-k chunk, 4 M-frags x 2 N-frags (even/odd l)
__device__ __forceinline__ void k2_comp2(const float2* bv, const short* puh, const short* pul,
                                         int ao, f32x4* accE, f32x4* accO) {
    bf16x8 bhE, blE, bhO, blO;
#pragma unroll
    for (int i = 0; i < 8; ++i) {
        bhE[i] = bfhi(bv[i].x); blE[i] = bflo(bv[i].x);
        bhO[i] = bfhi(bv[i].y); blO[i] = bflo(bv[i].y);
    }
#pragma unroll
    for (int m = 0; m < 4; ++m) {
        bf16x8 ah = *reinterpret_cast<const bf16x8*>(puh + ao + m * 128);
        bf16x8 al = *reinterpret_cast<const bf16x8*>(pul + ao + m * 128);
        accE[m] = __builtin_amdgcn_mfma_f32_16x16x32_bf16(al, bhE, accE[m], 0, 0, 0);
        accE[m] = __builtin_amdgcn_mfma_f32_16x16x32_bf16(ah, blE, accE[m], 0, 0, 0);
        accE[m] = __builtin_amdgcn_mfma_f32_16x16x32_bf16(ah, bhE, accE[m], 0, 0, 0);
        accO[m] = __builtin_amdgcn_mfma_f32_16x16x32_bf16(al, bhO, accO[m], 0, 0, 0);
        accO[m] = __builtin_amdgcn_mfma_f32_16x16x32_bf16(ah, blO, accO[m], 0, 0, 0);
        accO[m] = __builtin_amdgcn_mfma_f32_16x16x32_bf16(ah, bhO, accO[m], 0, 0, 0);
    }
}

// ---------------- Kernel 2 (split-bf16 MFMA, XCD-swizzled, paired N-frags, 4-way LDS k-reduce):
// part[ks][c][b][r][l] = sum_{k in half ks} u[b,r,k]*rw[c,r,k,l]
// Linear 1280-block grid; bid = lq*160 + (ks + 2r + 20c) so the 8 lq-siblings that
// share rw cache lines land on the SAME XCD (160 % 8 == 0) -> rw line fetched into one L2.
__global__ __launch_bounds__(256, 3) void k2_priors(const short* __restrict__ u_hi,
                                                    const short* __restrict__ u_lo,
                                                    const float* __restrict__ rw,
                                                    const int* __restrict__ task_p,
                                                    float* __restrict__ part) {
    const int bid = blockIdx.x;
    const int lq = bid / 160;
    const int rem = bid - lq * 160;          // ks + 2*(r + 10*c)
    const int ks = rem & 1;
    const int rc = rem >> 1;                 // r + 10*c
    const int c = rc / 10;
    const int r = rc - c * 10;
    if (r > *task_p) return;
    __shared__ float redS[3][2][16][64];
    const int t = threadIdx.x;
    const int L = t & 63, kh = t >> 6;           // kh 0..3
    const int colL = L & 15, kg = L >> 4;
    const int le = lq * 32 + 2 * colL;           // even l for this lane (odd = +1)
    const int kw0 = ks * 1024 + kh * 256;
    const int s00 = kw0 >> 3;

    f32x4 accE[4], accO[4];
#pragma unroll
    for (int m = 0; m < 4; ++m) {
        accE[m] = (f32x4){0.f, 0.f, 0.f, 0.f};
        accO[m] = (f32x4){0.f, 0.f, 0.f, 0.f};
    }

    const float* pb = rw + ((size_t)(c * NTq + r) * SCq + kw0 + kg * 8) * Sq + le;
    const short* puh = u_hi + (((size_t)r * 256 + s00 + kg) * 64 + colL) * 8;
    const short* pul = u_lo + (((size_t)r * 256 + s00 + kg) * 64 + colL) * 8;

    float2 bv0[8], bv1[8];
#pragma unroll
    for (int i = 0; i < 8; ++i) bv0[i] = *reinterpret_cast<const float2*>(pb + (size_t)i * Sq);

    for (int kc = 0; kc < 256; kc += 64) {
        {   // prefetch B chunk kc+32
            const float* p = pb + (size_t)(kc + 32) * Sq;
#pragma unroll
            for (int i = 0; i < 8; ++i) bv1[i] = *reinterpret_cast<const float2*>(p + (size_t)i * Sq);
        }
        __builtin_amdgcn_sched_barrier(0);
        k2_comp2(bv0, puh, pul, kc * 64, accE, accO);
        __builtin_amdgcn_sched_barrier(0);
        {   // prefetch B chunk kc+64 (dummy on last iter)
            int kn = (kc + 64 < 256) ? kc + 64 : 0;
            const float* p = pb + (size_t)kn * Sq;
#pragma unroll
            for (int i = 0; i < 8; ++i) bv0[i] = *reinterpret_cast<const float2*>(p + (size_t)i * Sq);
        }
        __builtin_amdgcn_sched_barrier(0);
        k2_comp2(bv1, puh, pul, (kc + 32) * 64, accE, accO);
        __builtin_amdgcn_sched_barrier(0);
    }

    // 4-way cross-kh reduction in LDS; kh==0 waves write out
    if (kh > 0) {
#pragma unroll
        for (int m = 0; m < 4; ++m)
#pragma unroll
            for (int g = 0; g < 4; ++g) {
                redS[kh - 1][0][m * 4 + g][L] = accE[m][g];
                redS[kh - 1][1][m * 4 + g][L] = accO[m][g];
            }
    }
    __syncthreads();
    if (kh == 0) {
#pragma unroll
        for (int m = 0; m < 4; ++m) {
#pragma unroll
            for (int g = 0; g < 4; ++g) {
                float vE = accE[m][g] + redS[0][0][m * 4 + g][L]
                         + redS[1][0][m * 4 + g][L] + redS[2][0][m * 4 + g][L];
                float vO = accO[m][g] + redS[0][1][m * 4 + g][L]
                         + redS[1][1][m * 4 + g][L] + redS[2][1][m * 4 + g][L];
                int bb = m * 16 + kg * 4 + g;
                size_t idx = (size_t)ks * 1310720 + ((size_t)(c * Bq + bb) * NTq + r) * Sq + le;
                float2 vv; vv.x = vE; vv.y = vO;
                *reinterpret_cast<float2*>(part + idx) = vv;
            }
        }
    }
}

// ---------------- Kernel 3+4 fused: routing per (c,b) + direct output projection.
__global__ __launch_bounds__(256) void k34_route_out(const float* __restrict__ part,
                                                     const int* __restrict__ task_p,
                                                     const float* __restrict__ lw,   // [768][8]
                                                     const float* __restrict__ lb,   // [768]
                                                     float* __restrict__ out) {      // [B,S,768]
    const int t = threadIdx.x;
    const int lane = t & 63, w = t >> 6;
    const int b = blockIdx.x & 63, c = blockIdx.x >> 6;
    const int task = *task_p;

    float pr[NTq][4];
    const float* p0 = part + ((size_t)(c * Bq + b) * NTq) * Sq + lane * 4;
#pragma unroll
    for (int r = 0; r < NTq; ++r) {
        f32x4 a = *reinterpret_cast<const f32x4*>(p0 + r * Sq);
        f32x4 d = *reinterpret_cast<const f32x4*>(p0 + 1310720 + r * Sq);
#pragma unroll
        for (int ii = 0; ii < 4; ++ii) pr[r][ii] = a[ii] + d[ii];
    }

    float logits[NTq];
#pragma unroll
    for (int r = 0; r < NTq; ++r) logits[r] = 0.f;
    float vote[4];

    for (int it = 0; it < 3; ++it) {
        float m = -1e30f;
#pragma unroll
        for (int r = 0; r < NTq; ++r) if (r <= task) m = fmaxf(m, logits[r]);
        float p[NTq]; float s = 0.f;
#pragma unroll
        for (int r = 0; r < NTq; ++r) {
            p[r] = (r <= task) ? expf(logits[r] - m) : 0.f;
            s += p[r];
        }
        float inv = 1.f / s;
#pragma unroll
        for (int ii = 0; ii < 4; ++ii) vote[ii] = 0.f;
#pragma unroll
        for (int r = 0; r < NTq; ++r) {
            float pw = p[r] * inv;
#pragma unroll
            for (int ii = 0; ii < 4; ++ii) vote[ii] = fmaf(pw, pr[r][ii], vote[ii]);
        }
        if (it == 2) break;

        float vals[11];
#pragma unroll
        for (int r = 0; r < NTq; ++r) {
            float d = 0.f;
#pragma unroll
            for (int ii = 0; ii < 4; ++ii) d = fmaf(pr[r][ii], vote[ii], d);
            vals[r] = d;
        }
        {
            float d = 0.f;
#pragma unroll
            for (int ii = 0; ii < 4; ++ii) d = fmaf(vote[ii], vote[ii], d);
            vals[10] = d;
        }
#pragma unroll
        for (int o = 32; o > 0; o >>= 1) {
#pragma unroll
            for (int v = 0; v < 11; ++v) vals[v] += __shfl_xor(vals[v], o, 64);
        }
        float sq = vals[10];
        float scale = (sq / (1.f + sq)) / sqrtf(sq);
#pragma unroll
        for (int r = 0; r < NTq; ++r)
            if (r <= task) logits[r] += scale * vals[r];
    }

    // ---- epilogue: wave w writes out rows rbase..rbase+7 (q = w*8+j), row j uses
    // vote[l], l = (w*8+j)*8 + jj, held in lanes 16w+2j (+1), regs jj&3.
    float v[8][8];
#pragma unroll
    for (int j = 0; j < 8; ++j) {
        int s0 = w * 16 + 2 * j;
#pragma unroll
        for (int ii = 0; ii < 4; ++ii) v[j][ii]     = __shfl(vote[ii], s0, 64);
#pragma unroll
        for (int ii = 0; ii < 4; ++ii) v[j][4 + ii] = __shfl(vote[ii], s0 + 1, 64);
    }
    const int rbase = c * 2048 + b * 32 + w * 8;
#pragma unroll
    for (int dd = 0; dd < 12; ++dd) {
        int d = lane + dd * 64;
        float4 wa = *reinterpret_cast<const float4*>(lw + (size_t)d * 8);
        float4 wb = *reinterpret_cast<const float4*>(lw + (size_t)d * 8 + 4);
        float lbv = lb[d];
#pragma unroll
        for (int j = 0; j < 8; ++j) {
            float acc = lbv;
            acc = fmaf(v[j][0], wa.x, acc);
            acc = fmaf(v[j][1], wa.y, acc);
            acc = fmaf(v[j][2], wa.z, acc);
            acc = fmaf(v[j][3], wa.w, acc);
            acc = fmaf(v[j][4], wb.x, acc);
            acc = fmaf(v[j][5], wb.y, acc);
            acc = fmaf(v[j][6], wb.z, acc);
            acc = fmaf(v[j][7], wb.w, acc);
            out[(size_t)(rbase + j) * Dq + d] = acc;
        }
    }
}

extern "C" void kernel_launch(void* const* d_in, const int* in_sizes, int n_in,
                              void* d_out, int out_size, void* d_ws, size_t ws_size,
                              hipStream_t stream) {
    const float* x    = (const float*)d_in[0];
    const int*   task = (const int*)d_in[1];
    const float* fc1w = (const float*)d_in[2];
    const float* fc1b = (const float*)d_in[3];
    const float* rw   = (const float*)d_in[4];
    const float* lw   = (const float*)d_in[5];
    const float* lb   = (const float*)d_in[6];
    float* out = (float*)d_out;

    short* u_hi = (short*)d_ws;                              // 2,621,440 B
    short* u_lo = u_hi + 1310720;                            // 2,621,440 B
    float* part = (float*)((char*)d_ws + 5242880);           // 10,485,760 B
    short* fwh  = (short*)((char*)d_ws + 16252928);          // 122,880 B
    short* fwl  = fwh + 61440;                               // 122,880 B

    k0_cvt<<<240, 256, 0, stream>>>(fc1w, fwh, fwl);
    k1_sem<<<1024, 256, 0, stream>>>(x, fwh, fwl, fc1b, u_hi, u_lo);
    k2_priors<<<1280, 256, 0, stream>>>(u_hi, u_lo, rw, task, part);
    k34_route_out<<<512, 256, 0, stream>>>(part, task, lw, lb, out);
}